// Round 1
// baseline (8179.697 us; speedup 1.0000x reference)
//
#include <hip/hip_runtime.h>

static constexpr int Bn = 32, Sn = 64, Tn = 64, Hn = 512, Vn = 32000;
static constexpr int H3 = 1536;  // 3*H

typedef __attribute__((ext_vector_type(8))) short bf16x8;
typedef __attribute__((ext_vector_type(4))) float f32x4;

__device__ __forceinline__ short f2bf(float f) {
    unsigned u = __float_as_uint(f);
    u += 0x7FFFu + ((u >> 16) & 1u);   // round-to-nearest-even
    return (short)(u >> 16);
}

// ---------------- prep: gather embedding rows -> bf16 ----------------
__global__ __launch_bounds__(128) void k_gather(const int* __restrict__ tgt,
                                                const float* __restrict__ emb,
                                                short* __restrict__ Xb) {
    int m = blockIdx.x;              // 0..2047  (= b*T + t)
    int c = threadIdx.x * 4;         // 128 threads * 4 = 512 cols
    const float4 v = *(const float4*)(emb + (long)tgt[m] * Hn + c);
    short4 o; o.x = f2bf(v.x); o.y = f2bf(v.y); o.z = f2bf(v.z); o.w = f2bf(v.w);
    *(short4*)(Xb + (long)m * Hn + c) = o;
}

// ---------------- prep: f32 -> bf16 convert (cols == 512, strided src) ----------------
__global__ __launch_bounds__(256) void k_cvt(const float* __restrict__ src, int src_ld,
                                             short* __restrict__ dst, long total4) {
    for (long i = (long)blockIdx.x * 256 + threadIdx.x; i < total4; i += (long)gridDim.x * 256) {
        long e = i * 4;
        long r = e >> 9; int c = (int)(e & 511);
        const float4 v = *(const float4*)(src + r * (long)src_ld + c);
        short4 o; o.x = f2bf(v.x); o.y = f2bf(v.y); o.z = f2bf(v.z); o.w = f2bf(v.w);
        *(short4*)(dst + e) = o;
    }
}

// ---------------- generic bf16 MFMA GEMM:  C[m][n] = sum_k A[m][k]*B[n][k] (+bias[n]) ----------------
// A: [M][K] k-contig (lda), B: [N][K] k-contig (ldb). Tile 128x128, BK=32, 256 thr (4 waves 2x2).
__global__ __launch_bounds__(256) void k_gemm_bf16(const short* __restrict__ A, int lda,
                                                   const short* __restrict__ Bm, int ldb,
                                                   const float* __restrict__ bias,
                                                   float* __restrict__ C, int ldc, int K) {
    __shared__ short lA[4096];   // [kg 0..3][row 0..127][j 0..7]
    __shared__ short lB[4096];
    const int tid = threadIdx.x;
    const int row0 = blockIdx.y * 128;
    const int col0 = blockIdx.x * 128;
    const int lane = tid & 63;
    const int w = tid >> 6;
    const int wr = w >> 1, wc = w & 1;       // 2x2 waves, each 64x64
    const int g = lane >> 4, rr = lane & 15;

    f32x4 acc[4][4];
    for (int m = 0; m < 4; ++m)
        for (int n = 0; n < 4; ++n)
            for (int q = 0; q < 4; ++q) acc[m][n][q] = 0.f;

    for (int kk = 0; kk < K; kk += 32) {
        for (int p = 0; p < 2; ++p) {
            int u = p * 256 + tid;               // 0..511
            int kg = u >> 7, r = u & 127;
            *(int4*)&lA[u * 8] = *(const int4*)(A + (long)(row0 + r) * lda + kk + kg * 8);
            *(int4*)&lB[u * 8] = *(const int4*)(Bm + (long)(col0 + r) * ldb + kk + kg * 8);
        }
        __syncthreads();
        bf16x8 av[4], bv[4];
        for (int m = 0; m < 4; ++m)
            av[m] = *(const bf16x8*)&lA[(g * 128 + wr * 64 + m * 16 + rr) * 8];
        for (int n = 0; n < 4; ++n)
            bv[n] = *(const bf16x8*)&lB[(g * 128 + wc * 64 + n * 16 + rr) * 8];
        for (int m = 0; m < 4; ++m)
            for (int n = 0; n < 4; ++n)
                acc[m][n] = __builtin_amdgcn_mfma_f32_16x16x32_bf16(av[m], bv[n], acc[m][n], 0, 0, 0);
        __syncthreads();
    }

    for (int n = 0; n < 4; ++n) {
        int gc = col0 + wc * 64 + n * 16 + rr;
        float bb = bias ? bias[gc] : 0.f;
        for (int m = 0; m < 4; ++m) {
            int gr = row0 + wr * 64 + m * 16 + g * 4;   // + q below (C/D: col=lane&15, row=4*(lane>>4)+reg)
            for (int q = 0; q < 4; ++q)
                C[(long)(gr + q) * ldc + gc] = acc[m][n][q] + bb;
        }
    }
}

// ---------------- recurrence: one block per batch element, 64 sequential steps ----------------
__global__ __launch_bounds__(1024) void k_recurrence(
    const float* __restrict__ GX,    // [B*T][1536]  (x @ W_ih^T + b_ih)
    const float* __restrict__ encW,  // [B*S][512]   (enc @ Wc1^T)
    const float* __restrict__ enc,   // [B][S][512]
    const void*  __restrict__ maskp, // [B][S] bool (dtype detected at runtime)
    const int*   __restrict__ fra,   // [B]
    const float* __restrict__ h0,    // [B][512]
    const float* __restrict__ W_hh,  // [1536][512]
    const float* __restrict__ b_hh,  // [1536]
    const float* __restrict__ W_cc,  // [512][1024]
    const float* __restrict__ b_cc,  // [512]
    short* __restrict__ ho_out)      // [B*T][512] bf16
{
    const int b = blockIdx.x;
    const int tid = threadIdx.x;
    __shared__ float h[512];
    __shared__ float hnew[512];
    __shared__ float ghp[3072];      // gh partials: row*2 + khalf
    __shared__ float sc[64];
    __shared__ float al[64];
    __shared__ float hop[2][512];

    if (tid < 512) h[tid] = h0[b * 512 + tid];
    // detect mask dtype: mask[0][0] is guaranteed true (src_len >= S/2)
    const unsigned w0 = ((const unsigned*)maskp)[0];
    const int mmode = (w0 == 1u) ? 0 : (w0 == 0x3F800000u ? 2 : 1);  // 0=int32, 2=f32, 1=byte
    const int flen = fra[b];
    __syncthreads();

    for (int t = 0; t < Tn; ++t) {
        // ---- gh partial dots: 3072 tasks of 256 MACs (balanced: 3 per thread)
        for (int q = 0; q < 3; ++q) {
            int task = tid + q * 1024;
            int row = task >> 1, half = task & 1;
            const float* wp = W_hh + (long)row * 512 + half * 256;
            const float* hp = h + half * 256;
            float acc = 0.f;
            #pragma unroll 8
            for (int k = 0; k < 256; k += 4) {
                float4 wv = *(const float4*)(wp + k);
                acc += wv.x * hp[k] + wv.y * hp[k + 1] + wv.z * hp[k + 2] + wv.w * hp[k + 3];
            }
            ghp[task] = acc;
        }
        __syncthreads();
        // ---- GRU elementwise
        if (tid < 512) {
            const float* gx = GX + (long)(b * Tn + t) * H3;
            float ghr = ghp[2 * tid] + ghp[2 * tid + 1] + b_hh[tid];
            float ghz = ghp[2 * (512 + tid)] + ghp[2 * (512 + tid) + 1] + b_hh[512 + tid];
            float ghn = ghp[2 * (1024 + tid)] + ghp[2 * (1024 + tid) + 1] + b_hh[1024 + tid];
            float r = 1.f / (1.f + expf(-(gx[tid] + ghr)));
            float z = 1.f / (1.f + expf(-(gx[512 + tid] + ghz)));
            float n = tanhf(gx[1024 + tid] + r * ghn);
            hnew[tid] = (1.f - z) * n + z * h[tid];
        }
        __syncthreads();
        // ---- attention scores: 16 threads per s
        {
            int s = tid >> 4, sub = tid & 15;
            const float* ep = enc + ((long)(b * Sn + s)) * 512 + sub * 32;
            const float* hp = hnew + sub * 32;
            float acc = 0.f;
            #pragma unroll 8
            for (int k = 0; k < 32; k += 4) {
                float4 ev = *(const float4*)(ep + k);
                acc += ev.x * hp[k] + ev.y * hp[k + 1] + ev.z * hp[k + 2] + ev.w * hp[k + 3];
            }
            acc += __shfl_xor(acc, 1);
            acc += __shfl_xor(acc, 2);
            acc += __shfl_xor(acc, 4);
            acc += __shfl_xor(acc, 8);
            if (sub == 0) {
                bool mv;
                if (mmode == 0)      mv = ((const int*)maskp)[b * Sn + s] != 0;
                else if (mmode == 1) mv = ((const unsigned char*)maskp)[b * Sn + s] != 0;
                else                 mv = ((const float*)maskp)[b * Sn + s] != 0.f;
                sc[s] = mv ? acc : -__builtin_inff();
            }
        }
        __syncthreads();
        // ---- softmax over S=64 (wave 0)
        if (tid < 64) {
            float v = sc[tid];
            float mx = v;
            for (int o = 1; o < 64; o <<= 1) mx = fmaxf(mx, __shfl_xor(mx, o));
            float e = expf(v - mx);          // exp(-inf) = 0
            float sum = e;
            for (int o = 1; o < 64; o <<= 1) sum += __shfl_xor(sum, o);
            al[tid] = e / sum;
        }
        __syncthreads();
        // ---- ho = tanh(Wc1*ctx + Wc2*h_new + b_cc); Wc1*ctx = sum_s al[s]*encW[b,s]
        {
            int j = tid & 511, part = tid >> 9;
            const float* wp = W_cc + (long)j * 1024 + 512 + part * 256;   // Wc2 half
            const float* hp = hnew + part * 256;
            float acc = 0.f;
            #pragma unroll 8
            for (int k = 0; k < 256; k += 4) {
                float4 wv = *(const float4*)(wp + k);
                acc += wv.x * hp[k] + wv.y * hp[k + 1] + wv.z * hp[k + 2] + wv.w * hp[k + 3];
            }
            if (part == 1) {
                const float* ew = encW + ((long)b * Sn) * 512 + j;
                float a2 = 0.f;
                #pragma unroll 8
                for (int s = 0; s < 64; ++s) a2 += al[s] * ew[s * 512];
                acc += a2 + b_cc[j];
            }
            hop[part][j] = acc;
        }
        __syncthreads();
        if (tid < 512) {
            float hv = tanhf(hop[0][tid] + hop[1][tid]);
            ho_out[((long)(b * Tn + t)) * 512 + tid] = f2bf(hv);
            h[tid] = (t < flen) ? hnew[tid] : h[tid];   // freeze finished sequences
        }
        __syncthreads();
    }
}

// ---------------- in-place log-softmax over V=32000 per row ----------------
__global__ __launch_bounds__(256) void k_logsoftmax(float* __restrict__ out) {
    const long row = blockIdx.x;
    float* p = out + row * (long)Vn;
    const int tid = threadIdx.x;
    __shared__ float redm[4];
    __shared__ float reds[4];

    float mx = -__builtin_inff();
    for (int i = tid; i < Vn / 4; i += 256) {
        float4 v = *(const float4*)(p + i * 4);
        mx = fmaxf(mx, fmaxf(fmaxf(v.x, v.y), fmaxf(v.z, v.w)));
    }
    for (int o = 1; o < 64; o <<= 1) mx = fmaxf(mx, __shfl_xor(mx, o));
    if ((tid & 63) == 0) redm[tid >> 6] = mx;
    __syncthreads();
    mx = fmaxf(fmaxf(redm[0], redm[1]), fmaxf(redm[2], redm[3]));

    float sum = 0.f;
    for (int i = tid; i < Vn / 4; i += 256) {
        float4 v = *(const float4*)(p + i * 4);
        sum += expf(v.x - mx) + expf(v.y - mx) + expf(v.z - mx) + expf(v.w - mx);
    }
    for (int o = 1; o < 64; o <<= 1) sum += __shfl_xor(sum, o);
    if ((tid & 63) == 0) reds[tid >> 6] = sum;
    __syncthreads();
    sum = reds[0] + reds[1] + reds[2] + reds[3];
    const float lse = mx + logf(sum);

    for (int i = tid; i < Vn / 4; i += 256) {
        float4 v = *(const float4*)(p + i * 4);
        v.x -= lse; v.y -= lse; v.z -= lse; v.w -= lse;
        *(float4*)(p + i * 4) = v;
    }
}

extern "C" void kernel_launch(void* const* d_in, const int* in_sizes, int n_in,
                              void* d_out, int out_size, void* d_ws, size_t ws_size,
                              hipStream_t stream) {
    const float* enc   = (const float*)d_in[0];
    const float* h0    = (const float*)d_in[1];   // [1,B,H] -> flat [B][512]
    const void*  maskp = d_in[2];
    const int*   tgt   = (const int*)d_in[3];
    const int*   fra   = (const int*)d_in[4];
    const float* emb   = (const float*)d_in[5];
    const float* W_ih  = (const float*)d_in[6];
    const float* W_hh  = (const float*)d_in[7];
    const float* b_ih  = (const float*)d_in[8];
    const float* b_hh  = (const float*)d_in[9];
    const float* W_cc  = (const float*)d_in[10];
    const float* b_cc  = (const float*)d_in[11];
    const float* W_out = (const float*)d_in[12];
    const float* b_out = (const float*)d_in[13];
    float* out = (float*)d_out;

    char* ws = (char*)d_ws;
    float* GX    = (float*)ws; ws += (long)2048 * 1536 * 4;   // 12.58 MB
    float* encW  = (float*)ws; ws += (long)2048 * 512 * 4;    //  4.19 MB
    short* ho_b  = (short*)ws; ws += (long)2048 * 512 * 2;    //  2.10 MB
    short* Xb    = (short*)ws; ws += (long)2048 * 512 * 2;    //  2.10 MB
    short* Wih_b = (short*)ws; ws += (long)1536 * 512 * 2;    //  1.57 MB
    short* Wc1_b = (short*)ws; ws += (long)512 * 512 * 2;     //  0.52 MB
    short* enc_b = (short*)ws; ws += (long)2048 * 512 * 2;    //  2.10 MB
    short* Wout_b= (short*)ws; ws += (long)32000 * 512 * 2;   // 32.77 MB  (total ~55.2 MB)

    // --- prep / converts
    k_gather<<<2048, 128, 0, stream>>>(tgt, emb, Xb);
    k_cvt<<<768, 256, 0, stream>>>(W_ih, 512, Wih_b, (long)1536 * 512 / 4);
    k_cvt<<<256, 256, 0, stream>>>(W_cc, 1024, Wc1_b, (long)512 * 512 / 4);   // Wc1 = W_cc[:, :512]
    k_cvt<<<1024, 256, 0, stream>>>(enc, 512, enc_b, (long)2048 * 512 / 4);
    k_cvt<<<4096, 256, 0, stream>>>(W_out, 512, Wout_b, (long)32000 * 512 / 4);

    // --- GX = X @ W_ih^T + b_ih   (M=2048, N=1536, K=512)
    k_gemm_bf16<<<dim3(12, 16), 256, 0, stream>>>(Xb, 512, Wih_b, 512, b_ih, GX, 1536, 512);
    // --- encW = enc @ Wc1^T       (M=2048, N=512, K=512)
    k_gemm_bf16<<<dim3(4, 16), 256, 0, stream>>>(enc_b, 512, Wc1_b, 512, nullptr, encW, 512, 512);

    // --- sequential recurrence, one block per batch element
    k_recurrence<<<32, 1024, 0, stream>>>(GX, encW, enc, maskp, fra, h0,
                                          W_hh, b_hh, W_cc, b_cc, ho_b);

    // --- logits = ho @ W_out^T + b_out   (M=2048, N=32000, K=512) -> d_out
    k_gemm_bf16<<<dim3(250, 16), 256, 0, stream>>>(ho_b, 512, Wout_b, 512, b_out, out, 32000, 512);

    // --- in-place log_softmax over V
    k_logsoftmax<<<2048, 256, 0, stream>>>(out);
}

// Round 3
// 5233.532 us; speedup vs baseline: 1.5629x; 1.5629x over previous
//
#include <hip/hip_runtime.h>

static constexpr int Bn = 32, Sn = 64, Tn = 64, Hn = 512, Vn = 32000;
static constexpr int H3 = 1536;  // 3*H

typedef __attribute__((ext_vector_type(8))) short bf16x8;
typedef __attribute__((ext_vector_type(4))) float f32x4;
typedef _Float16 h16;
typedef __attribute__((ext_vector_type(2))) _Float16 h16x2;
typedef __attribute__((ext_vector_type(8))) _Float16 h16x8;

__device__ __forceinline__ short f2bf(float f) {
    unsigned u = __float_as_uint(f);
    u += 0x7FFFu + ((u >> 16) & 1u);   // round-to-nearest-even
    return (short)(u >> 16);
}

// ---------------- prep: gather embedding rows -> bf16 ----------------
__global__ __launch_bounds__(128) void k_gather(const int* __restrict__ tgt,
                                                const float* __restrict__ emb,
                                                short* __restrict__ Xb) {
    int m = blockIdx.x;              // 0..2047  (= b*T + t)
    int c = threadIdx.x * 4;         // 128 threads * 4 = 512 cols
    const float4 v = *(const float4*)(emb + (long)tgt[m] * Hn + c);
    short4 o; o.x = f2bf(v.x); o.y = f2bf(v.y); o.z = f2bf(v.z); o.w = f2bf(v.w);
    *(short4*)(Xb + (long)m * Hn + c) = o;
}

// ---------------- prep: f32 -> bf16 convert (cols == 512, strided src) ----------------
__global__ __launch_bounds__(256) void k_cvt(const float* __restrict__ src, int src_ld,
                                             short* __restrict__ dst, long total4) {
    for (long i = (long)blockIdx.x * 256 + threadIdx.x; i < total4; i += (long)gridDim.x * 256) {
        long e = i * 4;
        long r = e >> 9; int c = (int)(e & 511);
        const float4 v = *(const float4*)(src + r * (long)src_ld + c);
        short4 o; o.x = f2bf(v.x); o.y = f2bf(v.y); o.z = f2bf(v.z); o.w = f2bf(v.w);
        *(short4*)(dst + e) = o;
    }
}

// ---------------- prep: f32 -> f16 convert (rows of 512, strided src with col offset) ----------------
__global__ __launch_bounds__(256) void k_cvt_f16(const float* __restrict__ src, int src_ld, int src_off,
                                                 h16* __restrict__ dst, long total8) {
    for (long i = (long)blockIdx.x * 256 + threadIdx.x; i < total8; i += (long)gridDim.x * 256) {
        long e = i * 8;
        long r = e >> 9; int c = (int)(e & 511);
        const float* sp = src + r * (long)src_ld + src_off + c;
        const float4 v0 = *(const float4*)(sp);
        const float4 v1 = *(const float4*)(sp + 4);
        h16x8 o;
        o[0] = (h16)v0.x; o[1] = (h16)v0.y; o[2] = (h16)v0.z; o[3] = (h16)v0.w;
        o[4] = (h16)v1.x; o[5] = (h16)v1.y; o[6] = (h16)v1.z; o[7] = (h16)v1.w;
        *(h16x8*)(dst + e) = o;
    }
}

// ---------------- generic bf16 MFMA GEMM:  C[m][n] = sum_k A[m][k]*B[n][k] (+bias[n]) ----------------
__global__ __launch_bounds__(256) void k_gemm_bf16(const short* __restrict__ A, int lda,
                                                   const short* __restrict__ Bm, int ldb,
                                                   const float* __restrict__ bias,
                                                   float* __restrict__ C, int ldc, int K) {
    __shared__ short lA[4096];   // [kg 0..3][row 0..127][j 0..7]
    __shared__ short lB[4096];
    const int tid = threadIdx.x;
    const int row0 = blockIdx.y * 128;
    const int col0 = blockIdx.x * 128;
    const int lane = tid & 63;
    const int w = tid >> 6;
    const int wr = w >> 1, wc = w & 1;       // 2x2 waves, each 64x64
    const int g = lane >> 4, rr = lane & 15;

    f32x4 acc[4][4];
    for (int m = 0; m < 4; ++m)
        for (int n = 0; n < 4; ++n)
            for (int q = 0; q < 4; ++q) acc[m][n][q] = 0.f;

    for (int kk = 0; kk < K; kk += 32) {
        for (int p = 0; p < 2; ++p) {
            int u = p * 256 + tid;               // 0..511
            int kg = u >> 7, r = u & 127;
            *(int4*)&lA[u * 8] = *(const int4*)(A + (long)(row0 + r) * lda + kk + kg * 8);
            *(int4*)&lB[u * 8] = *(const int4*)(Bm + (long)(col0 + r) * ldb + kk + kg * 8);
        }
        __syncthreads();
        bf16x8 av[4], bv[4];
        for (int m = 0; m < 4; ++m)
            av[m] = *(const bf16x8*)&lA[(g * 128 + wr * 64 + m * 16 + rr) * 8];
        for (int n = 0; n < 4; ++n)
            bv[n] = *(const bf16x8*)&lB[(g * 128 + wc * 64 + n * 16 + rr) * 8];
        for (int m = 0; m < 4; ++m)
            for (int n = 0; n < 4; ++n)
                acc[m][n] = __builtin_amdgcn_mfma_f32_16x16x32_bf16(av[m], bv[n], acc[m][n], 0, 0, 0);
        __syncthreads();
    }

    for (int n = 0; n < 4; ++n) {
        int gc = col0 + wc * 64 + n * 16 + rr;
        float bb = bias ? bias[gc] : 0.f;
        for (int m = 0; m < 4; ++m) {
            int gr = row0 + wr * 64 + m * 16 + g * 4;   // C/D: col=lane&15, row=4*(lane>>4)+reg
            for (int q = 0; q < 4; ++q)
                C[(long)(gr + q) * ldc + gc] = acc[m][n][q] + bb;
        }
    }
}

// ---------------- recurrence: one block per batch element, 64 sequential steps ----------------
// f16 weights (Whh_h, Wcc2_h) kept L2-resident; all state & accumulation in f32.
__global__ __launch_bounds__(1024) void k_recurrence(
    const float* __restrict__ GX,    // [B*T][1536]  (x @ W_ih^T + b_ih)
    const float* __restrict__ encW,  // [B*S][512]   (enc @ Wc1^T)
    const float* __restrict__ enc,   // [B][S][512]
    const void*  __restrict__ maskp, // [B][S] bool (dtype detected at runtime)
    const int*   __restrict__ fra,   // [B]
    const float* __restrict__ h0,    // [B][512]
    const h16*   __restrict__ Whh_h, // [1536][512] f16
    const float* __restrict__ b_hh,  // [1536]
    const h16*   __restrict__ Wcc2_h,// [512][512] f16  (= W_cc[:, 512:1024])
    const float* __restrict__ b_cc,  // [512]
    short* __restrict__ ho_out)      // [B*T][512] bf16
{
    const int b = blockIdx.x;
    const int tid = threadIdx.x;
    __shared__ __align__(16) float h[512];
    __shared__ __align__(16) h16 h16buf[512];
    __shared__ __align__(16) float hnew[512];
    __shared__ __align__(16) h16 hn16[512];
    __shared__ float ghp[3072];      // gh partials: row*2 + khalf
    __shared__ float sc[64];
    __shared__ float al[64];
    __shared__ float hop[2][512];

    if (tid < 512) {
        float v = h0[b * 512 + tid];
        h[tid] = v;
        h16buf[tid] = (h16)v;
    }
    // detect mask dtype: mask[0][0] is guaranteed true (src_len >= S/2)
    const unsigned w0 = ((const unsigned*)maskp)[0];
    const int mmode = (w0 == 1u) ? 0 : (w0 == 0x3F800000u ? 2 : 1);  // 0=int32, 2=f32, 1=byte
    const int flen = fra[b];
    __syncthreads();

    for (int t = 0; t < Tn; ++t) {
        // ---- gh partial dots: 3072 tasks of 256 MACs, v_dot2_f32_f16
        for (int q = 0; q < 3; ++q) {
            int task = tid + q * 1024;
            int row = task >> 1, half = task & 1;
            const h16x8* wp = (const h16x8*)(Whh_h + (long)row * 512 + half * 256);
            const h16x8* hp = (const h16x8*)(h16buf + half * 256);
            float acc = 0.f;
            #pragma unroll
            for (int k = 0; k < 32; ++k) {
                h16x8 wv = wp[k];
                h16x8 hv = hp[k];
                h16x2 w0v = {wv[0], wv[1]}, w1v = {wv[2], wv[3]}, w2v = {wv[4], wv[5]}, w3v = {wv[6], wv[7]};
                h16x2 h0v = {hv[0], hv[1]}, h1v = {hv[2], hv[3]}, h2v = {hv[4], hv[5]}, h3v = {hv[6], hv[7]};
                acc = __builtin_amdgcn_fdot2(w0v, h0v, acc, false);
                acc = __builtin_amdgcn_fdot2(w1v, h1v, acc, false);
                acc = __builtin_amdgcn_fdot2(w2v, h2v, acc, false);
                acc = __builtin_amdgcn_fdot2(w3v, h3v, acc, false);
            }
            ghp[task] = acc;
        }
        __syncthreads();
        // ---- GRU elementwise
        if (tid < 512) {
            const float* gx = GX + (long)(b * Tn + t) * H3;
            float ghr = ghp[2 * tid] + ghp[2 * tid + 1] + b_hh[tid];
            float ghz = ghp[2 * (512 + tid)] + ghp[2 * (512 + tid) + 1] + b_hh[512 + tid];
            float ghn = ghp[2 * (1024 + tid)] + ghp[2 * (1024 + tid) + 1] + b_hh[1024 + tid];
            float r = 1.f / (1.f + expf(-(gx[tid] + ghr)));
            float z = 1.f / (1.f + expf(-(gx[512 + tid] + ghz)));
            float n = tanhf(gx[1024 + tid] + r * ghn);
            float hv = (1.f - z) * n + z * h[tid];
            hnew[tid] = hv;
            hn16[tid] = (h16)hv;
        }
        __syncthreads();
        // ---- attention scores: 16 threads per s (f32 enc, f32 h_new)
        {
            int s = tid >> 4, sub = tid & 15;
            const float* ep = enc + ((long)(b * Sn + s)) * 512 + sub * 32;
            const float* hp = hnew + sub * 32;
            float acc = 0.f;
            #pragma unroll 8
            for (int k = 0; k < 32; k += 4) {
                float4 ev = *(const float4*)(ep + k);
                acc += ev.x * hp[k] + ev.y * hp[k + 1] + ev.z * hp[k + 2] + ev.w * hp[k + 3];
            }
            acc += __shfl_xor(acc, 1);
            acc += __shfl_xor(acc, 2);
            acc += __shfl_xor(acc, 4);
            acc += __shfl_xor(acc, 8);
            if (sub == 0) {
                bool mv;
                if (mmode == 0)      mv = ((const int*)maskp)[b * Sn + s] != 0;
                else if (mmode == 1) mv = ((const unsigned char*)maskp)[b * Sn + s] != 0;
                else                 mv = ((const float*)maskp)[b * Sn + s] != 0.f;
                sc[s] = mv ? acc : -__builtin_inff();
            }
        }
        __syncthreads();
        // ---- softmax over S=64 (wave 0)
        if (tid < 64) {
            float v = sc[tid];
            float mx = v;
            for (int o = 1; o < 64; o <<= 1) mx = fmaxf(mx, __shfl_xor(mx, o));
            float e = expf(v - mx);          // exp(-inf) = 0
            float sum = e;
            for (int o = 1; o < 64; o <<= 1) sum += __shfl_xor(sum, o);
            al[tid] = e / sum;
        }
        __syncthreads();
        // ---- ho = tanh(Wc1*ctx + Wc2*h_new + b_cc); Wc1*ctx = sum_s al[s]*encW[b,s]
        {
            int j = tid & 511, part = tid >> 9;
            const h16x8* wp = (const h16x8*)(Wcc2_h + (long)j * 512 + part * 256);
            const h16x8* hp = (const h16x8*)(hn16 + part * 256);
            float acc = 0.f;
            #pragma unroll
            for (int k = 0; k < 32; ++k) {
                h16x8 wv = wp[k];
                h16x8 hv = hp[k];
                h16x2 w0v = {wv[0], wv[1]}, w1v = {wv[2], wv[3]}, w2v = {wv[4], wv[5]}, w3v = {wv[6], wv[7]};
                h16x2 h0v = {hv[0], hv[1]}, h1v = {hv[2], hv[3]}, h2v = {hv[4], hv[5]}, h3v = {hv[6], hv[7]};
                acc = __builtin_amdgcn_fdot2(w0v, h0v, acc, false);
                acc = __builtin_amdgcn_fdot2(w1v, h1v, acc, false);
                acc = __builtin_amdgcn_fdot2(w2v, h2v, acc, false);
                acc = __builtin_amdgcn_fdot2(w3v, h3v, acc, false);
            }
            if (part == 1) {
                const float* ew = encW + ((long)b * Sn) * 512 + j;
                float a2 = 0.f;
                #pragma unroll 8
                for (int s = 0; s < 64; ++s) a2 += al[s] * ew[s * 512];
                acc += a2 + b_cc[j];
            }
            hop[part][j] = acc;
        }
        __syncthreads();
        if (tid < 512) {
            float hv = tanhf(hop[0][tid] + hop[1][tid]);
            ho_out[((long)(b * Tn + t)) * 512 + tid] = f2bf(hv);
            float hkeep = (t < flen) ? hnew[tid] : h[tid];   // freeze finished sequences
            h[tid] = hkeep;
            h16buf[tid] = (h16)hkeep;
        }
        __syncthreads();
    }
}

// ---------------- in-place log-softmax over V=32000 per row ----------------
__global__ __launch_bounds__(256) void k_logsoftmax(float* __restrict__ out) {
    const long row = blockIdx.x;
    float* p = out + row * (long)Vn;
    const int tid = threadIdx.x;
    __shared__ float redm[4];
    __shared__ float reds[4];

    float mx = -__builtin_inff();
    for (int i = tid; i < Vn / 4; i += 256) {
        float4 v = *(const float4*)(p + i * 4);
        mx = fmaxf(mx, fmaxf(fmaxf(v.x, v.y), fmaxf(v.z, v.w)));
    }
    for (int o = 1; o < 64; o <<= 1) mx = fmaxf(mx, __shfl_xor(mx, o));
    if ((tid & 63) == 0) redm[tid >> 6] = mx;
    __syncthreads();
    mx = fmaxf(fmaxf(redm[0], redm[1]), fmaxf(redm[2], redm[3]));

    float sum = 0.f;
    for (int i = tid; i < Vn / 4; i += 256) {
        float4 v = *(const float4*)(p + i * 4);
        sum += expf(v.x - mx) + expf(v.y - mx) + expf(v.z - mx) + expf(v.w - mx);
    }
    for (int o = 1; o < 64; o <<= 1) sum += __shfl_xor(sum, o);
    if ((tid & 63) == 0) reds[tid >> 6] = sum;
    __syncthreads();
    sum = reds[0] + reds[1] + reds[2] + reds[3];
    const float lse = mx + logf(sum);

    for (int i = tid; i < Vn / 4; i += 256) {
        float4 v = *(const float4*)(p + i * 4);
        v.x -= lse; v.y -= lse; v.z -= lse; v.w -= lse;
        *(float4*)(p + i * 4) = v;
    }
}

extern "C" void kernel_launch(void* const* d_in, const int* in_sizes, int n_in,
                              void* d_out, int out_size, void* d_ws, size_t ws_size,
                              hipStream_t stream) {
    const float* enc   = (const float*)d_in[0];
    const float* h0    = (const float*)d_in[1];   // [1,B,H] -> flat [B][512]
    const void*  maskp = d_in[2];
    const int*   tgt   = (const int*)d_in[3];
    const int*   fra   = (const int*)d_in[4];
    const float* emb   = (const float*)d_in[5];
    const float* W_ih  = (const float*)d_in[6];
    const float* W_hh  = (const float*)d_in[7];
    const float* b_ih  = (const float*)d_in[8];
    const float* b_hh  = (const float*)d_in[9];
    const float* W_cc  = (const float*)d_in[10];
    const float* b_cc  = (const float*)d_in[11];
    const float* W_out = (const float*)d_in[12];
    const float* b_out = (const float*)d_in[13];
    float* out = (float*)d_out;

    char* ws = (char*)d_ws;
    float* GX    = (float*)ws; ws += (long)2048 * 1536 * 4;   // 12.58 MB
    float* encW  = (float*)ws; ws += (long)2048 * 512 * 4;    //  4.19 MB
    short* ho_b  = (short*)ws; ws += (long)2048 * 512 * 2;    //  2.10 MB
    short* Xb    = (short*)ws; ws += (long)2048 * 512 * 2;    //  2.10 MB
    short* Wih_b = (short*)ws; ws += (long)1536 * 512 * 2;    //  1.57 MB
    short* Wc1_b = (short*)ws; ws += (long)512 * 512 * 2;     //  0.52 MB
    short* enc_b = (short*)ws; ws += (long)2048 * 512 * 2;    //  2.10 MB
    short* Wout_b= (short*)ws; ws += (long)32000 * 512 * 2;   // 32.77 MB
    h16*  Whh_h  = (h16*)ws;  ws += (long)1536 * 512 * 2;     //  1.57 MB
    h16*  Wcc2_h = (h16*)ws;  ws += (long)512 * 512 * 2;      //  0.52 MB  (total ~57.3 MB)

    // --- prep / converts
    k_gather<<<2048, 128, 0, stream>>>(tgt, emb, Xb);
    k_cvt<<<768, 256, 0, stream>>>(W_ih, 512, Wih_b, (long)1536 * 512 / 4);
    k_cvt<<<256, 256, 0, stream>>>(W_cc, 1024, Wc1_b, (long)512 * 512 / 4);   // Wc1 = W_cc[:, :512]
    k_cvt<<<1024, 256, 0, stream>>>(enc, 512, enc_b, (long)2048 * 512 / 4);
    k_cvt<<<4096, 256, 0, stream>>>(W_out, 512, Wout_b, (long)32000 * 512 / 4);
    k_cvt_f16<<<384, 256, 0, stream>>>(W_hh, 512, 0, Whh_h, (long)1536 * 512 / 8);
    k_cvt_f16<<<128, 256, 0, stream>>>(W_cc, 1024, 512, Wcc2_h, (long)512 * 512 / 8);  // Wc2 = W_cc[:, 512:]

    // --- GX = X @ W_ih^T + b_ih   (M=2048, N=1536, K=512)
    k_gemm_bf16<<<dim3(12, 16), 256, 0, stream>>>(Xb, 512, Wih_b, 512, b_ih, GX, 1536, 512);
    // --- encW = enc @ Wc1^T       (M=2048, N=512, K=512)
    k_gemm_bf16<<<dim3(4, 16), 256, 0, stream>>>(enc_b, 512, Wc1_b, 512, nullptr, encW, 512, 512);

    // --- sequential recurrence, one block per batch element
    k_recurrence<<<32, 1024, 0, stream>>>(GX, encW, enc, maskp, fra, h0,
                                          Whh_h, b_hh, Wcc2_h, b_cc, ho_b);

    // --- logits = ho @ W_out^T + b_out   (M=2048, N=32000, K=512) -> d_out
    k_gemm_bf16<<<dim3(250, 16), 256, 0, stream>>>(ho_b, 512, Wout_b, 512, b_out, out, 32000, 512);

    // --- in-place log_softmax over V
    k_logsoftmax<<<2048, 256, 0, stream>>>(out);
}

// Round 4
// 2153.380 us; speedup vs baseline: 3.7985x; 2.4304x over previous
//
#include <hip/hip_runtime.h>

static constexpr int Bn = 32, Sn = 64, Tn = 64, Hn = 512, Vn = 32000;
static constexpr int H3 = 1536;   // 3*H
static constexpr int NBLK = 64;   // 32 weight-blocks + 32 batch-blocks

typedef __attribute__((ext_vector_type(8))) short bf16x8;
typedef __attribute__((ext_vector_type(4))) float f32x4;

__device__ __forceinline__ short f2bf(float f) {
    unsigned u = __float_as_uint(f);
    u += 0x7FFFu + ((u >> 16) & 1u);   // round-to-nearest-even
    return (short)(u >> 16);
}
__device__ __forceinline__ float bf2f(short s) {
    return __uint_as_float(((unsigned)(unsigned short)s) << 16);
}

// ---------------- prep: gather embedding rows -> bf16 ----------------
__global__ __launch_bounds__(128) void k_gather(const int* __restrict__ tgt,
                                                const float* __restrict__ emb,
                                                short* __restrict__ Xb) {
    int m = blockIdx.x;
    int c = threadIdx.x * 4;
    const float4 v = *(const float4*)(emb + (long)tgt[m] * Hn + c);
    short4 o; o.x = f2bf(v.x); o.y = f2bf(v.y); o.z = f2bf(v.z); o.w = f2bf(v.w);
    *(short4*)(Xb + (long)m * Hn + c) = o;
}

// ---------------- prep: flat f32 -> bf16 ----------------
__global__ __launch_bounds__(256) void k_cvt_flat(const float* __restrict__ src,
                                                  short* __restrict__ dst, long n4) {
    for (long i = (long)blockIdx.x * 256 + threadIdx.x; i < n4; i += (long)gridDim.x * 256) {
        const float4 v = *(const float4*)(src + i * 4);
        short4 o; o.x = f2bf(v.x); o.y = f2bf(v.y); o.z = f2bf(v.z); o.w = f2bf(v.w);
        *(short4*)(dst + i * 4) = o;
    }
}

// ---------------- generic bf16 MFMA GEMM:  C[m][n] = sum_k A[m][k]*B[n][k] (+bias[n]) ----------------
__global__ __launch_bounds__(256) void k_gemm_bf16(const short* __restrict__ A, int lda,
                                                   const short* __restrict__ Bm, int ldb,
                                                   const float* __restrict__ bias,
                                                   float* __restrict__ C, int ldc, int K) {
    __shared__ short lA[4096];
    __shared__ short lB[4096];
    const int tid = threadIdx.x;
    const int row0 = blockIdx.y * 128;
    const int col0 = blockIdx.x * 128;
    const int lane = tid & 63;
    const int w = tid >> 6;
    const int wr = w >> 1, wc = w & 1;
    const int g = lane >> 4, rr = lane & 15;

    f32x4 acc[4][4];
    for (int m = 0; m < 4; ++m)
        for (int n = 0; n < 4; ++n)
            for (int q = 0; q < 4; ++q) acc[m][n][q] = 0.f;

    for (int kk = 0; kk < K; kk += 32) {
        for (int p = 0; p < 2; ++p) {
            int u = p * 256 + tid;
            int kg = u >> 7, r = u & 127;
            *(int4*)&lA[u * 8] = *(const int4*)(A + (long)(row0 + r) * lda + kk + kg * 8);
            *(int4*)&lB[u * 8] = *(const int4*)(Bm + (long)(col0 + r) * ldb + kk + kg * 8);
        }
        __syncthreads();
        bf16x8 av[4], bv[4];
        for (int m = 0; m < 4; ++m)
            av[m] = *(const bf16x8*)&lA[(g * 128 + wr * 64 + m * 16 + rr) * 8];
        for (int n = 0; n < 4; ++n)
            bv[n] = *(const bf16x8*)&lB[(g * 128 + wc * 64 + n * 16 + rr) * 8];
        for (int m = 0; m < 4; ++m)
            for (int n = 0; n < 4; ++n)
                acc[m][n] = __builtin_amdgcn_mfma_f32_16x16x32_bf16(av[m], bv[n], acc[m][n], 0, 0, 0);
        __syncthreads();
    }

    for (int n = 0; n < 4; ++n) {
        int gc = col0 + wc * 64 + n * 16 + rr;
        float bb = bias ? bias[gc] : 0.f;
        for (int m = 0; m < 4; ++m) {
            int gr = row0 + wr * 64 + m * 16 + g * 4;   // C/D: col=lane&15, row=4*(lane>>4)+q
            for (int q = 0; q < 4; ++q)
                C[(long)(gr + q) * ldc + gc] = acc[m][n][q] + bb;
        }
    }
}

// ---------------- persistent-weight cooperative recurrence ----------------
// blocks 0..31  ("W-blocks"): W_hh rows [bid*48,+48) and W_cc rows [bid*16,+16) in VGPRs (MFMA A-frags)
// blocks 32..63 ("B-blocks"): batch element b=bid-32; h-state in regs, enc[b] bf16 in LDS
struct WSm {
    short h16[Bn * Hn];   // frozen h, bf16, swizzled   (32 KB)
    short hn[Bn * Hn];    // h_new(t-1), bf16, swizzled (32 KB)
    short ctx[Bn * Hn];   // ctx(t-1), bf16, swizzled   (32 KB)
    int   flen[Bn];
};
struct BSm {
    short encl[Sn * 520]; // enc[b] bf16, rows padded to 520 (66.6 KB)
    float scp[8][64];
    float al[64];
    short hnf[Hn];
};
union USm { WSm w; BSm b; };

__device__ __forceinline__ void grid_barrier(unsigned* flags, unsigned gen) {
    __syncthreads();
    if (threadIdx.x == 0) {
        __threadfence();   // write-back local L2 (release)
        __hip_atomic_store(flags + blockIdx.x * 16, gen, __ATOMIC_RELEASE, __HIP_MEMORY_SCOPE_AGENT);
    }
    if (threadIdx.x < NBLK) {
        while (__hip_atomic_load(flags + threadIdx.x * 16, __ATOMIC_RELAXED, __HIP_MEMORY_SCOPE_AGENT) < gen)
            __builtin_amdgcn_s_sleep(1);
    }
    __syncthreads();
    __threadfence();       // invalidate local caches (acquire)
}

__global__ __launch_bounds__(512, 1) void k_seq(
    const float* __restrict__ GX, const float* __restrict__ enc,
    const void* __restrict__ maskp, const int* __restrict__ fra,
    const float* __restrict__ h0,
    const short* __restrict__ Whh_b, const float* __restrict__ b_hh,
    const short* __restrict__ Wcc_b, const float* __restrict__ b_cc,
    short* __restrict__ ho_out,
    float* __restrict__ gh_ws, short* __restrict__ hn_ws, short* __restrict__ ctx_ws,
    unsigned* __restrict__ flags)
{
    __shared__ __align__(16) USm sm;
    const int bid = blockIdx.x;
    const int tid = threadIdx.x;
    const int wv = tid >> 6, lane = tid & 63;
    unsigned gen = 0;

    bf16x8 afr[32];
    int flen_b = 0, mmode = 0;
    float h_reg = 0.f;

    if (bid < Bn) {
        // ---- W-block setup: load A-fragments once into registers
        const int ke = (lane >> 4) * 8;
        if (wv < 6) {
            const int row = bid * 48 + (wv >> 1) * 16 + (lane & 15);
            #pragma unroll
            for (int k = 0; k < 16; ++k)
                afr[k] = *(const bf16x8*)(Whh_b + (long)row * 512 + k * 32 + ke);
        } else {
            const int row = bid * 16 + (lane & 15);
            #pragma unroll
            for (int k = 0; k < 32; ++k)
                afr[k] = *(const bf16x8*)(Wcc_b + (long)row * 1024 + k * 32 + ke);
        }
        if (tid < Bn) sm.w.flen[tid] = fra[tid];
    } else {
        // ---- B-block setup: enc[b] -> LDS (bf16), h0 -> regs, publish initial h
        const int b = bid - Bn;
        flen_b = fra[b];
        const unsigned w0 = ((const unsigned*)maskp)[0];
        mmode = (w0 == 1u) ? 0 : (w0 == 0x3F800000u ? 2 : 1);  // int32 / f32 / byte
        h_reg = h0[b * Hn + tid];
        hn_ws[b * Hn + tid] = f2bf(h_reg);
        const float* encb = enc + (long)b * (Sn * Hn);
        #pragma unroll
        for (int it = 0; it < 16; ++it) {
            int e = (it * 512 + tid) * 4;
            float4 v = *(const float4*)(encb + e);
            int s = e >> 9, k = e & 511;
            short4 o; o.x = f2bf(v.x); o.y = f2bf(v.y); o.z = f2bf(v.z); o.w = f2bf(v.w);
            *(short4*)(sm.b.encl + s * 520 + k) = o;
        }
    }
    gen++; grid_barrier(flags, gen);

    for (int t = 0; t <= Tn; ++t) {
        // ================= phase X (W-blocks) =================
        if (bid < Bn) {
            // stage hn(t-1)/ctx(t-1) -> LDS (swizzled) and freeze-merge into h16
            #pragma unroll
            for (int it = 0; it < 4; ++it) {
                const int idx = it * 512 + tid;            // 16B chunk id (b*64 + c)
                const int b = idx >> 6, c = idx & 63;
                const int soff = b * 512 + ((c ^ (b & 7)) << 3);
                int4 v1 = *(const int4*)(hn_ws + idx * 8);
                *(int4*)(sm.w.hn + soff) = v1;
                if (t - 1 < sm.w.flen[b]) *(int4*)(sm.w.h16 + soff) = v1;
                int4 v2 = *(const int4*)(ctx_ws + idx * 8);
                *(int4*)(sm.w.ctx + soff) = v2;
            }
            __syncthreads();
            if (wv < 6) {
                if (t < Tn) {          // gh(t) = W_hh_slice @ h_all
                    const int m = wv >> 1, n = wv & 1;
                    const int bq = n * 16 + (lane & 15);
                    f32x4 acc = {0.f, 0.f, 0.f, 0.f};
                    #pragma unroll
                    for (int k = 0; k < 16; ++k) {
                        const int c = k * 4 + (lane >> 4);
                        bf16x8 bfr = *(const bf16x8*)(sm.w.h16 + bq * 512 + ((c ^ (bq & 7)) << 3));
                        acc = __builtin_amdgcn_mfma_f32_16x16x32_bf16(afr[k], bfr, acc, 0, 0, 0);
                    }
                    const int r0 = bid * 48 + m * 16 + ((lane >> 4) << 2);
                    #pragma unroll
                    for (int q = 0; q < 4; ++q)
                        gh_ws[bq * H3 + r0 + q] = acc[q];
                }
            } else if (t > 0) {        // ho(t-1) = tanh(W_cc_slice @ [ctx; h_new] + b_cc)
                const int n = wv - 6;
                const int bq = n * 16 + (lane & 15);
                f32x4 acc = {0.f, 0.f, 0.f, 0.f};
                #pragma unroll
                for (int k = 0; k < 32; ++k) {
                    const int c = (k & 15) * 4 + (lane >> 4);
                    const short* src = (k < 16) ? sm.w.ctx : sm.w.hn;
                    bf16x8 bfr = *(const bf16x8*)(src + bq * 512 + ((c ^ (bq & 7)) << 3));
                    acc = __builtin_amdgcn_mfma_f32_16x16x32_bf16(afr[k], bfr, acc, 0, 0, 0);
                }
                const int j0 = bid * 16 + ((lane >> 4) << 2);
                short4 o;
                o.x = f2bf(tanhf(acc[0] + b_cc[j0 + 0]));
                o.y = f2bf(tanhf(acc[1] + b_cc[j0 + 1]));
                o.z = f2bf(tanhf(acc[2] + b_cc[j0 + 2]));
                o.w = f2bf(tanhf(acc[3] + b_cc[j0 + 3]));
                *(short4*)(ho_out + ((long)(bq * Tn + (t - 1))) * Hn + j0) = o;
            }
        }
        if (t == Tn) break;
        gen++; grid_barrier(flags, gen);

        // ================= phase Y (B-blocks) =================
        if (bid >= Bn) {
            const int b = bid - Bn;
            const float* gx = GX + (long)(b * Tn + t) * H3;
            const float ghr = gh_ws[b * H3 + tid] + b_hh[tid];
            const float ghz = gh_ws[b * H3 + 512 + tid] + b_hh[512 + tid];
            const float ghn = gh_ws[b * H3 + 1024 + tid] + b_hh[1024 + tid];
            const float r = 1.f / (1.f + expf(-(gx[tid] + ghr)));
            const float z = 1.f / (1.f + expf(-(gx[512 + tid] + ghz)));
            const float nn = tanhf(gx[1024 + tid] + r * ghn);
            const float hv = (1.f - z) * nn + z * h_reg;
            const short hb = f2bf(hv);
            sm.b.hnf[tid] = hb;
            hn_ws[b * Hn + tid] = hb;
            h_reg = (t < flen_b) ? hv : h_reg;      // freeze finished sequences
            __syncthreads();
            {   // attention score partials: wave `sub` covers k-slice, lane = s
                const int s = tid & 63, sub = tid >> 6;
                const short* erow = sm.b.encl + s * 520 + sub * 64;
                const short* hrow = sm.b.hnf + sub * 64;
                float p = 0.f;
                #pragma unroll
                for (int c8 = 0; c8 < 8; ++c8) {
                    bf16x8 ev = *(const bf16x8*)(erow + c8 * 8);
                    bf16x8 hv8 = *(const bf16x8*)(hrow + c8 * 8);
                    #pragma unroll
                    for (int e = 0; e < 8; ++e)
                        p += bf2f(ev[e]) * bf2f(hv8[e]);
                }
                sm.b.scp[sub][s] = p;
            }
            __syncthreads();
            if (tid < 64) {             // mask + softmax over S=64 (wave 0)
                float v = 0.f;
                #pragma unroll
                for (int u = 0; u < 8; ++u) v += sm.b.scp[u][tid];
                bool mv;
                if (mmode == 0)      mv = ((const int*)maskp)[b * Sn + tid] != 0;
                else if (mmode == 1) mv = ((const unsigned char*)maskp)[b * Sn + tid] != 0;
                else                 mv = ((const float*)maskp)[b * Sn + tid] != 0.f;
                v = mv ? v : -__builtin_inff();
                float mx = v;
                for (int o = 1; o < 64; o <<= 1) mx = fmaxf(mx, __shfl_xor(mx, o));
                float e = expf(v - mx);
                float su = e;
                for (int o = 1; o < 64; o <<= 1) su += __shfl_xor(su, o);
                sm.b.al[tid] = e / su;
            }
            __syncthreads();
            {   // raw ctx = sum_s al[s] * enc[b,s,:]
                float cx = 0.f;
                #pragma unroll 8
                for (int s = 0; s < 64; ++s)
                    cx += sm.b.al[s] * bf2f(sm.b.encl[s * 520 + tid]);
                ctx_ws[b * Hn + tid] = f2bf(cx);
            }
        }
        gen++; grid_barrier(flags, gen);
    }
}

// ---------------- in-place log-softmax over V=32000 per row ----------------
__global__ __launch_bounds__(256) void k_logsoftmax(float* __restrict__ out) {
    const long row = blockIdx.x;
    float* p = out + row * (long)Vn;
    const int tid = threadIdx.x;
    __shared__ float redm[4];
    __shared__ float reds[4];

    float mx = -__builtin_inff();
    for (int i = tid; i < Vn / 4; i += 256) {
        float4 v = *(const float4*)(p + i * 4);
        mx = fmaxf(mx, fmaxf(fmaxf(v.x, v.y), fmaxf(v.z, v.w)));
    }
    for (int o = 1; o < 64; o <<= 1) mx = fmaxf(mx, __shfl_xor(mx, o));
    if ((tid & 63) == 0) redm[tid >> 6] = mx;
    __syncthreads();
    mx = fmaxf(fmaxf(redm[0], redm[1]), fmaxf(redm[2], redm[3]));

    float sum = 0.f;
    for (int i = tid; i < Vn / 4; i += 256) {
        float4 v = *(const float4*)(p + i * 4);
        sum += expf(v.x - mx) + expf(v.y - mx) + expf(v.z - mx) + expf(v.w - mx);
    }
    for (int o = 1; o < 64; o <<= 1) sum += __shfl_xor(sum, o);
    if ((tid & 63) == 0) reds[tid >> 6] = sum;
    __syncthreads();
    sum = reds[0] + reds[1] + reds[2] + reds[3];
    const float lse = mx + logf(sum);

    for (int i = tid; i < Vn / 4; i += 256) {
        float4 v = *(const float4*)(p + i * 4);
        v.x -= lse; v.y -= lse; v.z -= lse; v.w -= lse;
        *(float4*)(p + i * 4) = v;
    }
}

extern "C" void kernel_launch(void* const* d_in, const int* in_sizes, int n_in,
                              void* d_out, int out_size, void* d_ws, size_t ws_size,
                              hipStream_t stream) {
    const float* enc   = (const float*)d_in[0];
    const float* h0    = (const float*)d_in[1];
    const void*  maskp = d_in[2];
    const int*   tgt   = (const int*)d_in[3];
    const int*   fra   = (const int*)d_in[4];
    const float* emb   = (const float*)d_in[5];
    const float* W_ih  = (const float*)d_in[6];
    const float* W_hh  = (const float*)d_in[7];
    const float* b_ih  = (const float*)d_in[8];
    const float* b_hh  = (const float*)d_in[9];
    const float* W_cc  = (const float*)d_in[10];
    const float* b_cc  = (const float*)d_in[11];
    const float* W_out = (const float*)d_in[12];
    const float* b_out = (const float*)d_in[13];
    float* out = (float*)d_out;

    char* ws = (char*)d_ws;
    float*    GX     = (float*)ws;    ws += (long)2048 * 1536 * 4;  // 12.58 MB
    short*    Xb     = (short*)ws;    ws += (long)2048 * 512 * 2;   //  2.10 MB
    short*    Wih_b  = (short*)ws;    ws += (long)1536 * 512 * 2;   //  1.57 MB
    short*    Wout_b = (short*)ws;    ws += (long)32000 * 512 * 2;  // 32.77 MB
    short*    Whh_b  = (short*)ws;    ws += (long)1536 * 512 * 2;   //  1.57 MB
    short*    Wcc_b  = (short*)ws;    ws += (long)512 * 1024 * 2;   //  1.05 MB
    short*    ho_b   = (short*)ws;    ws += (long)2048 * 512 * 2;   //  2.10 MB
    float*    gh_ws  = (float*)ws;    ws += (long)32 * 1536 * 4;    //  0.20 MB
    short*    hn_ws  = (short*)ws;    ws += (long)32 * 512 * 2;
    short*    ctx_ws = (short*)ws;    ws += (long)32 * 512 * 2;
    unsigned* flags  = (unsigned*)ws; ws += 4096;                   // total ~54 MB

    // --- prep / converts
    k_gather<<<2048, 128, 0, stream>>>(tgt, emb, Xb);
    k_cvt_flat<<<768, 256, 0, stream>>>(W_ih, Wih_b, (long)1536 * 512 / 4);
    k_cvt_flat<<<4096, 256, 0, stream>>>(W_out, Wout_b, (long)32000 * 512 / 4);
    k_cvt_flat<<<768, 256, 0, stream>>>(W_hh, Whh_b, (long)1536 * 512 / 4);
    k_cvt_flat<<<512, 256, 0, stream>>>(W_cc, Wcc_b, (long)512 * 1024 / 4);

    // --- GX = X @ W_ih^T + b_ih   (M=2048, N=1536, K=512)
    k_gemm_bf16<<<dim3(12, 16), 256, 0, stream>>>(Xb, 512, Wih_b, 512, b_ih, GX, 1536, 512);

    // --- cooperative recurrence (64 co-resident blocks, custom grid barrier)
    hipMemsetAsync(flags, 0, 4096, stream);
    k_seq<<<NBLK, 512, 0, stream>>>(GX, enc, maskp, fra, h0,
                                    Whh_b, b_hh, Wcc_b, b_cc,
                                    ho_b, gh_ws, hn_ws, ctx_ws, flags);

    // --- logits = ho @ W_out^T + b_out   (M=2048, N=32000, K=512) -> d_out
    k_gemm_bf16<<<dim3(250, 16), 256, 0, stream>>>(ho_b, 512, Wout_b, 512, b_out, out, 32000, 512);

    // --- in-place log_softmax over V
    k_logsoftmax<<<2048, 256, 0, stream>>>(out);
}

// Round 5
// 846.738 us; speedup vs baseline: 9.6602x; 2.5431x over previous
//
#include <hip/hip_runtime.h>

static constexpr int Bn = 32, Sn = 64, Tn = 64, Hn = 512, Vn = 32000;
static constexpr int H3 = 1536;   // 3*H
static constexpr int NBLK = 64;   // 32 weight-blocks + 32 batch-blocks

typedef __attribute__((ext_vector_type(8))) short bf16x8;
typedef __attribute__((ext_vector_type(4))) float f32x4;

__device__ __forceinline__ short f2bf(float f) {
    unsigned u = __float_as_uint(f);
    u += 0x7FFFu + ((u >> 16) & 1u);   // round-to-nearest-even
    return (short)(u >> 16);
}
__device__ __forceinline__ float bf2f(short s) {
    return __uint_as_float(((unsigned)(unsigned short)s) << 16);
}

// ---------------- prep: gather embedding rows -> bf16 ----------------
__global__ __launch_bounds__(128) void k_gather(const int* __restrict__ tgt,
                                                const float* __restrict__ emb,
                                                short* __restrict__ Xb) {
    int m = blockIdx.x;
    int c = threadIdx.x * 4;
    const float4 v = *(const float4*)(emb + (long)tgt[m] * Hn + c);
    short4 o; o.x = f2bf(v.x); o.y = f2bf(v.y); o.z = f2bf(v.z); o.w = f2bf(v.w);
    *(short4*)(Xb + (long)m * Hn + c) = o;
}

// ---------------- prep: flat f32 -> bf16 ----------------
__global__ __launch_bounds__(256) void k_cvt_flat(const float* __restrict__ src,
                                                  short* __restrict__ dst, long n4) {
    for (long i = (long)blockIdx.x * 256 + threadIdx.x; i < n4; i += (long)gridDim.x * 256) {
        const float4 v = *(const float4*)(src + i * 4);
        short4 o; o.x = f2bf(v.x); o.y = f2bf(v.y); o.z = f2bf(v.z); o.w = f2bf(v.w);
        *(short4*)(dst + i * 4) = o;
    }
}

// ---------------- generic bf16 MFMA GEMM:  C[m][n] = sum_k A[m][k]*B[n][k] (+bias[n]) ----------------
__global__ __launch_bounds__(256) void k_gemm_bf16(const short* __restrict__ A, int lda,
                                                   const short* __restrict__ Bm, int ldb,
                                                   const float* __restrict__ bias,
                                                   float* __restrict__ C, int ldc, int K) {
    __shared__ short lA[4096];
    __shared__ short lB[4096];
    const int tid = threadIdx.x;
    const int row0 = blockIdx.y * 128;
    const int col0 = blockIdx.x * 128;
    const int lane = tid & 63;
    const int w = tid >> 6;
    const int wr = w >> 1, wc = w & 1;
    const int g = lane >> 4, rr = lane & 15;

    f32x4 acc[4][4];
    for (int m = 0; m < 4; ++m)
        for (int n = 0; n < 4; ++n)
            for (int q = 0; q < 4; ++q) acc[m][n][q] = 0.f;

    for (int kk = 0; kk < K; kk += 32) {
        for (int p = 0; p < 2; ++p) {
            int u = p * 256 + tid;
            int kg = u >> 7, r = u & 127;
            *(int4*)&lA[u * 8] = *(const int4*)(A + (long)(row0 + r) * lda + kk + kg * 8);
            *(int4*)&lB[u * 8] = *(const int4*)(Bm + (long)(col0 + r) * ldb + kk + kg * 8);
        }
        __syncthreads();
        bf16x8 av[4], bv[4];
        for (int m = 0; m < 4; ++m)
            av[m] = *(const bf16x8*)&lA[(g * 128 + wr * 64 + m * 16 + rr) * 8];
        for (int n = 0; n < 4; ++n)
            bv[n] = *(const bf16x8*)&lB[(g * 128 + wc * 64 + n * 16 + rr) * 8];
        for (int m = 0; m < 4; ++m)
            for (int n = 0; n < 4; ++n)
                acc[m][n] = __builtin_amdgcn_mfma_f32_16x16x32_bf16(av[m], bv[n], acc[m][n], 0, 0, 0);
        __syncthreads();
    }

    for (int n = 0; n < 4; ++n) {
        int gc = col0 + wc * 64 + n * 16 + rr;
        float bb = bias ? bias[gc] : 0.f;
        for (int m = 0; m < 4; ++m) {
            int gr = row0 + wr * 64 + m * 16 + g * 4;   // C/D: col=lane&15, row=4*(lane>>4)+q
            for (int q = 0; q < 4; ++q)
                C[(long)(gr + q) * ldc + gc] = acc[m][n][q] + bb;
        }
    }
}

// ---------------- persistent-weight cooperative recurrence (fence-free handshakes) ----------------
// blocks 0..31  ("W"): W_hh rows [bid*48,+48) + W_cc rows [bid*16,+16) in VGPRs
// blocks 32..63 ("B"): batch element b=bid-32; h in regs, enc[b] bf16 in LDS
// All cross-block data moves via sc1 (coherent-point) atomics; flags via relaxed atomics
// with per-wave s_waitcnt vmcnt(0) + __syncthreads release discipline. No __threadfence.
struct WSm {
    short h16[Bn * Hn];   // frozen h, bf16, swizzled   (32 KB)
    short hn[Bn * Hn];    // h_new(t-1), bf16, swizzled (32 KB)
    short ctx[Bn * Hn];   // ctx(t-1), bf16, swizzled   (32 KB)
    int   flen[Bn];
};
struct BSm {
    short encl[Sn * 520]; // enc[b] bf16, rows padded to 520 (66.6 KB)
    float scp[8][64];
    float al[64];
    short hnf[Hn];
};
union USm { WSm w; BSm b; };

__device__ __forceinline__ void sig_flag(unsigned* slot, unsigned val) {
    asm volatile("s_waitcnt vmcnt(0)" ::: "memory");   // drain this wave's sc1 stores
    __syncthreads();                                   // all waves drained
    if (threadIdx.x == 0)
        __hip_atomic_store(slot, val, __ATOMIC_RELAXED, __HIP_MEMORY_SCOPE_AGENT);
}
__device__ __forceinline__ void wait_flags32(const unsigned* base, unsigned need) {
    if (threadIdx.x < 32) {
        while (__hip_atomic_load(base + threadIdx.x * 32, __ATOMIC_RELAXED, __HIP_MEMORY_SCOPE_AGENT) < need)
            __builtin_amdgcn_s_sleep(1);
    }
    __syncthreads();
}

__global__ __launch_bounds__(512, 1) void k_seq(
    const float* __restrict__ GX, const float* __restrict__ enc,
    const void* __restrict__ maskp, const int* __restrict__ fra,
    const float* __restrict__ h0,
    const short* __restrict__ Whh_b, const float* __restrict__ b_hh,
    const short* __restrict__ Wcc_b, const float* __restrict__ b_cc,
    short* __restrict__ ho_out,
    float* __restrict__ gh_ws,                  // [32][1536] f32 (sc1)
    unsigned long long* __restrict__ hn_q,      // [32][128]  4xbf16 (sc1)
    unsigned long long* __restrict__ ctx_q,     // [2][32][128] 4xbf16 (sc1, dbuf)
    unsigned* __restrict__ flags)               // [3][32][32] W / Bh / Bc
{
    __shared__ __align__(16) USm sm;
    const int bid = blockIdx.x;
    const int tid = threadIdx.x;
    const int wv = tid >> 6, lane = tid & 63;

    unsigned* flagW  = flags;
    unsigned* flagBh = flags + 1024;
    unsigned* flagBc = flags + 2048;

    if (bid < Bn) {
        // ================= W-block =================
        bf16x8 afr[32];
        const int ke = (lane >> 4) * 8;
        if (wv < 6) {
            const int row = bid * 48 + (wv >> 1) * 16 + (lane & 15);
            #pragma unroll
            for (int k = 0; k < 16; ++k)
                afr[k] = *(const bf16x8*)(Whh_b + (long)row * 512 + k * 32 + ke);
        } else {
            const int row = bid * 16 + (lane & 15);
            #pragma unroll
            for (int k = 0; k < 32; ++k)
                afr[k] = *(const bf16x8*)(Wcc_b + (long)row * 1024 + k * 32 + ke);
        }
        if (tid < Bn) sm.w.flen[tid] = fra[tid];

        for (int t = 0; t <= Tn; ++t) {
            // ---- wait hn(t-1), stage + freeze-merge
            wait_flags32(flagBh, (unsigned)(t + 1));
            #pragma unroll
            for (int it = 0; it < 8; ++it) {
                const int idx2 = it * 512 + tid;          // 8B unit: b*128 + ci2
                const int b = idx2 >> 7, ci2 = idx2 & 127;
                const int soff = b * 512 + ((((ci2 >> 1)) ^ (b & 7)) << 3) + (ci2 & 1) * 4;
                const unsigned long long v = __hip_atomic_load(hn_q + idx2, __ATOMIC_RELAXED, __HIP_MEMORY_SCOPE_AGENT);
                *(unsigned long long*)&sm.w.hn[soff] = v;
                if (t - 1 < sm.w.flen[b]) *(unsigned long long*)&sm.w.h16[soff] = v;
            }
            __syncthreads();
            if (t < Tn) {
                if (wv < 6) {          // gh(t) = W_hh_slice @ h_all
                    const int m = wv >> 1, n = wv & 1;
                    const int bq = n * 16 + (lane & 15);
                    f32x4 acc = {0.f, 0.f, 0.f, 0.f};
                    #pragma unroll
                    for (int k = 0; k < 16; ++k) {
                        const int c = k * 4 + (lane >> 4);
                        bf16x8 bfr = *(const bf16x8*)(sm.w.h16 + bq * 512 + ((c ^ (bq & 7)) << 3));
                        acc = __builtin_amdgcn_mfma_f32_16x16x32_bf16(afr[k], bfr, acc, 0, 0, 0);
                    }
                    const int r0 = bid * 48 + m * 16 + ((lane >> 4) << 2);
                    unsigned long long g01 = ((unsigned long long)__float_as_uint(acc[1]) << 32) | __float_as_uint(acc[0]);
                    unsigned long long g23 = ((unsigned long long)__float_as_uint(acc[3]) << 32) | __float_as_uint(acc[2]);
                    unsigned long long* gq = (unsigned long long*)gh_ws + ((bq * H3 + r0) >> 1);
                    __hip_atomic_store(gq,     g01, __ATOMIC_RELAXED, __HIP_MEMORY_SCOPE_AGENT);
                    __hip_atomic_store(gq + 1, g23, __ATOMIC_RELAXED, __HIP_MEMORY_SCOPE_AGENT);
                }
                sig_flag(flagW + bid * 32, (unsigned)(t + 1));
            }
            if (t > 0) {
                // ---- wait ctx(t-1), stage, compute ho(t-1) off the critical path
                wait_flags32(flagBc, (unsigned)t);
                const unsigned long long* cq = ctx_q + (((t - 1) & 1) ? 4096 : 0);
                #pragma unroll
                for (int it = 0; it < 8; ++it) {
                    const int idx2 = it * 512 + tid;
                    const int b = idx2 >> 7, ci2 = idx2 & 127;
                    const int soff = b * 512 + ((((ci2 >> 1)) ^ (b & 7)) << 3) + (ci2 & 1) * 4;
                    *(unsigned long long*)&sm.w.ctx[soff] =
                        __hip_atomic_load(cq + idx2, __ATOMIC_RELAXED, __HIP_MEMORY_SCOPE_AGENT);
                }
                __syncthreads();
                if (wv >= 6) {         // ho(t-1) = tanh(W_cc_slice @ [ctx; h_new] + b_cc)
                    const int n = wv - 6;
                    const int bq = n * 16 + (lane & 15);
                    f32x4 acc = {0.f, 0.f, 0.f, 0.f};
                    #pragma unroll
                    for (int k = 0; k < 32; ++k) {
                        const int c = (k & 15) * 4 + (lane >> 4);
                        const short* src = (k < 16) ? sm.w.ctx : sm.w.hn;
                        bf16x8 bfr = *(const bf16x8*)(src + bq * 512 + ((c ^ (bq & 7)) << 3));
                        acc = __builtin_amdgcn_mfma_f32_16x16x32_bf16(afr[k], bfr, acc, 0, 0, 0);
                    }
                    const int j0 = bid * 16 + ((lane >> 4) << 2);
                    short4 o;
                    o.x = f2bf(tanhf(acc[0] + b_cc[j0 + 0]));
                    o.y = f2bf(tanhf(acc[1] + b_cc[j0 + 1]));
                    o.z = f2bf(tanhf(acc[2] + b_cc[j0 + 2]));
                    o.w = f2bf(tanhf(acc[3] + b_cc[j0 + 3]));
                    *(short4*)(ho_out + ((long)(bq * Tn + (t - 1))) * Hn + j0) = o;
                }
            }
        }
    } else {
        // ================= B-block =================
        const int b = bid - Bn;
        const int flen_b = fra[b];
        const unsigned w0 = ((const unsigned*)maskp)[0];
        const int mmode = (w0 == 1u) ? 0 : (w0 == 0x3F800000u ? 2 : 1);  // int32 / f32 / byte
        float h_reg = h0[b * Hn + tid];

        {   // enc[b] -> LDS (bf16)
            const float* encb = enc + (long)b * (Sn * Hn);
            #pragma unroll
            for (int it = 0; it < 16; ++it) {
                int e = (it * 512 + tid) * 4;
                float4 v = *(const float4*)(encb + e);
                int s = e >> 9, k = e & 511;
                short4 o; o.x = f2bf(v.x); o.y = f2bf(v.y); o.z = f2bf(v.z); o.w = f2bf(v.w);
                *(short4*)(sm.b.encl + s * 520 + k) = o;
            }
        }
        {   // publish h(-1) = h0 (packed 4x bf16)
            int hbw = (int)(unsigned short)f2bf(h_reg);
            int n1 = __shfl_down(hbw, 1);
            int n2 = __shfl_down(hbw, 2);
            int n3 = __shfl_down(hbw, 3);
            if ((tid & 3) == 0) {
                unsigned long long pk = (unsigned long long)(unsigned)(hbw | (n1 << 16))
                                      | ((unsigned long long)(unsigned)(n2 | (n3 << 16)) << 32);
                __hip_atomic_store(hn_q + b * 128 + (tid >> 2), pk, __ATOMIC_RELAXED, __HIP_MEMORY_SCOPE_AGENT);
            }
        }
        sig_flag(flagBh + b * 32, 1u);

        for (int t = 0; t < Tn; ++t) {
            wait_flags32(flagW, (unsigned)(t + 1));
            // ---- GRU elementwise (gh via sc1 loads)
            const float* gx = GX + (long)(b * Tn + t) * H3;
            const float ghr = __hip_atomic_load(gh_ws + b * H3 + tid,        __ATOMIC_RELAXED, __HIP_MEMORY_SCOPE_AGENT) + b_hh[tid];
            const float ghz = __hip_atomic_load(gh_ws + b * H3 + 512 + tid,  __ATOMIC_RELAXED, __HIP_MEMORY_SCOPE_AGENT) + b_hh[512 + tid];
            const float ghn = __hip_atomic_load(gh_ws + b * H3 + 1024 + tid, __ATOMIC_RELAXED, __HIP_MEMORY_SCOPE_AGENT) + b_hh[1024 + tid];
            const float r = 1.f / (1.f + expf(-(gx[tid] + ghr)));
            const float z = 1.f / (1.f + expf(-(gx[512 + tid] + ghz)));
            const float nn = tanhf(gx[1024 + tid] + r * ghn);
            const float hv = (1.f - z) * nn + z * h_reg;
            const short hb = f2bf(hv);
            sm.b.hnf[tid] = hb;
            h_reg = (t < flen_b) ? hv : h_reg;      // freeze finished sequences
            {   // publish hn(t) immediately (critical path for W's gh(t+1))
                int hbw = (int)(unsigned short)hb;
                int n1 = __shfl_down(hbw, 1);
                int n2 = __shfl_down(hbw, 2);
                int n3 = __shfl_down(hbw, 3);
                if ((tid & 3) == 0) {
                    unsigned long long pk = (unsigned long long)(unsigned)(hbw | (n1 << 16))
                                          | ((unsigned long long)(unsigned)(n2 | (n3 << 16)) << 32);
                    __hip_atomic_store(hn_q + b * 128 + (tid >> 2), pk, __ATOMIC_RELAXED, __HIP_MEMORY_SCOPE_AGENT);
                }
            }
            sig_flag(flagBh + b * 32, (unsigned)(t + 2));

            // ---- attention (off the gh critical path)
            {   // score partials: wave `sub` covers k-slice, lane = s
                const int s = tid & 63, sub = tid >> 6;
                const short* erow = sm.b.encl + s * 520 + sub * 64;
                const short* hrow = sm.b.hnf + sub * 64;
                float p = 0.f;
                #pragma unroll
                for (int c8 = 0; c8 < 8; ++c8) {
                    bf16x8 ev = *(const bf16x8*)(erow + c8 * 8);
                    bf16x8 hv8 = *(const bf16x8*)(hrow + c8 * 8);
                    #pragma unroll
                    for (int e = 0; e < 8; ++e)
                        p += bf2f(ev[e]) * bf2f(hv8[e]);
                }
                sm.b.scp[sub][s] = p;
            }
            __syncthreads();
            if (tid < 64) {             // mask + softmax over S=64 (wave 0)
                float v = 0.f;
                #pragma unroll
                for (int u = 0; u < 8; ++u) v += sm.b.scp[u][tid];
                bool mv;
                if (mmode == 0)      mv = ((const int*)maskp)[b * Sn + tid] != 0;
                else if (mmode == 1) mv = ((const unsigned char*)maskp)[b * Sn + tid] != 0;
                else                 mv = ((const float*)maskp)[b * Sn + tid] != 0.f;
                v = mv ? v : -__builtin_inff();
                float mx = v;
                for (int o = 1; o < 64; o <<= 1) mx = fmaxf(mx, __shfl_xor(mx, o));
                float e = expf(v - mx);
                float su = e;
                for (int o = 1; o < 64; o <<= 1) su += __shfl_xor(su, o);
                sm.b.al[tid] = e / su;
            }
            __syncthreads();
            {   // raw ctx = sum_s al[s] * enc[b,s,:]; publish to slot t&1
                float cx = 0.f;
                #pragma unroll 8
                for (int s = 0; s < 64; ++s)
                    cx += sm.b.al[s] * bf2f(sm.b.encl[s * 520 + tid]);
                int cbw = (int)(unsigned short)f2bf(cx);
                int n1 = __shfl_down(cbw, 1);
                int n2 = __shfl_down(cbw, 2);
                int n3 = __shfl_down(cbw, 3);
                if ((tid & 3) == 0) {
                    unsigned long long pk = (unsigned long long)(unsigned)(cbw | (n1 << 16))
                                          | ((unsigned long long)(unsigned)(n2 | (n3 << 16)) << 32);
                    __hip_atomic_store(ctx_q + ((t & 1) ? 4096 : 0) + b * 128 + (tid >> 2), pk,
                                       __ATOMIC_RELAXED, __HIP_MEMORY_SCOPE_AGENT);
                }
            }
            sig_flag(flagBc + b * 32, (unsigned)(t + 1));
        }
    }
}

// ---------------- in-place log-softmax over V=32000 per row ----------------
__global__ __launch_bounds__(256) void k_logsoftmax(float* __restrict__ out) {
    const long row = blockIdx.x;
    float* p = out + row * (long)Vn;
    const int tid = threadIdx.x;
    __shared__ float redm[4];
    __shared__ float reds[4];

    float mx = -__builtin_inff();
    for (int i = tid; i < Vn / 4; i += 256) {
        float4 v = *(const float4*)(p + i * 4);
        mx = fmaxf(mx, fmaxf(fmaxf(v.x, v.y), fmaxf(v.z, v.w)));
    }
    for (int o = 1; o < 64; o <<= 1) mx = fmaxf(mx, __shfl_xor(mx, o));
    if ((tid & 63) == 0) redm[tid >> 6] = mx;
    __syncthreads();
    mx = fmaxf(fmaxf(redm[0], redm[1]), fmaxf(redm[2], redm[3]));

    float sum = 0.f;
    for (int i = tid; i < Vn / 4; i += 256) {
        float4 v = *(const float4*)(p + i * 4);
        sum += expf(v.x - mx) + expf(v.y - mx) + expf(v.z - mx) + expf(v.w - mx);
    }
    for (int o = 1; o < 64; o <<= 1) sum += __shfl_xor(sum, o);
    if ((tid & 63) == 0) reds[tid >> 6] = sum;
    __syncthreads();
    sum = reds[0] + reds[1] + reds[2] + reds[3];
    const float lse = mx + logf(sum);

    for (int i = tid; i < Vn / 4; i += 256) {
        float4 v = *(const float4*)(p + i * 4);
        v.x -= lse; v.y -= lse; v.z -= lse; v.w -= lse;
        *(float4*)(p + i * 4) = v;
    }
}

extern "C" void kernel_launch(void* const* d_in, const int* in_sizes, int n_in,
                              void* d_out, int out_size, void* d_ws, size_t ws_size,
                              hipStream_t stream) {
    const float* enc   = (const float*)d_in[0];
    const float* h0    = (const float*)d_in[1];
    const void*  maskp = d_in[2];
    const int*   tgt   = (const int*)d_in[3];
    const int*   fra   = (const int*)d_in[4];
    const float* emb   = (const float*)d_in[5];
    const float* W_ih  = (const float*)d_in[6];
    const float* W_hh  = (const float*)d_in[7];
    const float* b_ih  = (const float*)d_in[8];
    const float* b_hh  = (const float*)d_in[9];
    const float* W_cc  = (const float*)d_in[10];
    const float* b_cc  = (const float*)d_in[11];
    const float* W_out = (const float*)d_in[12];
    const float* b_out = (const float*)d_in[13];
    float* out = (float*)d_out;

    char* ws = (char*)d_ws;
    float*    GX     = (float*)ws;    ws += (long)2048 * 1536 * 4;  // 12.58 MB
    short*    Xb     = (short*)ws;    ws += (long)2048 * 512 * 2;   //  2.10 MB
    short*    Wih_b  = (short*)ws;    ws += (long)1536 * 512 * 2;   //  1.57 MB
    short*    Wout_b = (short*)ws;    ws += (long)32000 * 512 * 2;  // 32.77 MB
    short*    Whh_b  = (short*)ws;    ws += (long)1536 * 512 * 2;   //  1.57 MB
    short*    Wcc_b  = (short*)ws;    ws += (long)512 * 1024 * 2;   //  1.05 MB
    short*    ho_b   = (short*)ws;    ws += (long)2048 * 512 * 2;   //  2.10 MB
    float*    gh_ws  = (float*)ws;    ws += (long)32 * 1536 * 4;    //  0.20 MB
    unsigned long long* hn_q  = (unsigned long long*)ws; ws += (long)32 * 128 * 8;      // 32 KB
    unsigned long long* ctx_q = (unsigned long long*)ws; ws += (long)2 * 32 * 128 * 8;  // 64 KB
    unsigned* flags  = (unsigned*)ws; ws += 3 * 1024 * 4;           // 12 KB flags (W/Bh/Bc)

    // --- prep / converts
    k_gather<<<2048, 128, 0, stream>>>(tgt, emb, Xb);
    k_cvt_flat<<<768, 256, 0, stream>>>(W_ih, Wih_b, (long)1536 * 512 / 4);
    k_cvt_flat<<<4096, 256, 0, stream>>>(W_out, Wout_b, (long)32000 * 512 / 4);
    k_cvt_flat<<<768, 256, 0, stream>>>(W_hh, Whh_b, (long)1536 * 512 / 4);
    k_cvt_flat<<<512, 256, 0, stream>>>(W_cc, Wcc_b, (long)512 * 1024 / 4);

    // --- GX = X @ W_ih^T + b_ih   (M=2048, N=1536, K=512)
    k_gemm_bf16<<<dim3(12, 16), 256, 0, stream>>>(Xb, 512, Wih_b, 512, b_ih, GX, 1536, 512);

    // --- cooperative recurrence (64 co-resident blocks, fence-free handshakes)
    hipMemsetAsync(flags, 0, 3 * 1024 * 4, stream);
    k_seq<<<NBLK, 512, 0, stream>>>(GX, enc, maskp, fra, h0,
                                    Whh_b, b_hh, Wcc_b, b_cc,
                                    ho_b, gh_ws, hn_q, ctx_q, flags);

    // --- logits = ho @ W_out^T + b_out   (M=2048, N=32000, K=512) -> d_out
    k_gemm_bf16<<<dim3(250, 16), 256, 0, stream>>>(ho_b, 512, Wout_b, 512, b_out, out, 32000, 512);

    // --- in-place log_softmax over V
    k_logsoftmax<<<2048, 256, 0, stream>>>(out);
}

// Round 7
// 754.509 us; speedup vs baseline: 10.8411x; 1.1222x over previous
//
#include <hip/hip_runtime.h>

static constexpr int Bn = 32, Sn = 64, Tn = 64, Hn = 512, Vn = 32000;
static constexpr int H3 = 1536;   // 3*H
static constexpr int NBLK = 64;   // 32 weight/GRU-blocks + 32 attention-blocks

typedef __attribute__((ext_vector_type(8))) short bf16x8;
typedef __attribute__((ext_vector_type(4))) float f32x4;

__device__ __forceinline__ short f2bf(float f) {
    unsigned u = __float_as_uint(f);
    u += 0x7FFFu + ((u >> 16) & 1u);   // round-to-nearest-even
    return (short)(u >> 16);
}
__device__ __forceinline__ float bf2f(short s) {
    return __uint_as_float(((unsigned)(unsigned short)s) << 16);
}

// async global->LDS, 16B per lane (dest must be linear in lane order)
__device__ __forceinline__ void gload16(const void* g, void* l) {
    __builtin_amdgcn_global_load_lds(
        (const __attribute__((address_space(1))) unsigned int*)g,
        (__attribute__((address_space(3))) unsigned int*)l, 16, 0, 0);
}

// ---------------- prep: gather embedding rows -> bf16 ----------------
__global__ __launch_bounds__(128) void k_gather(const int* __restrict__ tgt,
                                                const float* __restrict__ emb,
                                                short* __restrict__ Xb) {
    int m = blockIdx.x;
    int c = threadIdx.x * 4;
    const float4 v = *(const float4*)(emb + (long)tgt[m] * Hn + c);
    short4 o; o.x = f2bf(v.x); o.y = f2bf(v.y); o.z = f2bf(v.z); o.w = f2bf(v.w);
    *(short4*)(Xb + (long)m * Hn + c) = o;
}

// ---------------- prep: f32 -> bf16 (dst rows of 512; strided src with col offset) ----------------
__global__ __launch_bounds__(256) void k_cvt(const float* __restrict__ src, int src_ld, int src_off,
                                             short* __restrict__ dst, long total4) {
    for (long i = (long)blockIdx.x * 256 + threadIdx.x; i < total4; i += (long)gridDim.x * 256) {
        long e = i * 4;
        long r = e >> 9; int c = (int)(e & 511);
        const float4 v = *(const float4*)(src + r * (long)src_ld + src_off + c);
        short4 o; o.x = f2bf(v.x); o.y = f2bf(v.y); o.z = f2bf(v.z); o.w = f2bf(v.w);
        *(short4*)(dst + e) = o;
    }
}

// ---------------- generic bf16 MFMA GEMM:  C[m][n] = sum_k A[m][k]*B[n][k] (+bias[n]) ----------------
__global__ __launch_bounds__(256) void k_gemm_bf16(const short* __restrict__ A, int lda,
                                                   const short* __restrict__ Bm, int ldb,
                                                   const float* __restrict__ bias,
                                                   float* __restrict__ C, int ldc, int K) {
    __shared__ short lA[4096];
    __shared__ short lB[4096];
    const int tid = threadIdx.x;
    const int row0 = blockIdx.y * 128;
    const int col0 = blockIdx.x * 128;
    const int lane = tid & 63;
    const int w = tid >> 6;
    const int wr = w >> 1, wc = w & 1;
    const int g = lane >> 4, rr = lane & 15;

    f32x4 acc[4][4];
    for (int m = 0; m < 4; ++m)
        for (int n = 0; n < 4; ++n)
            for (int q = 0; q < 4; ++q) acc[m][n][q] = 0.f;

    for (int kk = 0; kk < K; kk += 32) {
        for (int p = 0; p < 2; ++p) {
            int u = p * 256 + tid;
            int kg = u >> 7, r = u & 127;
            gload16(A + (long)(row0 + r) * lda + kk + kg * 8, &lA[u * 8]);
            gload16(Bm + (long)(col0 + r) * ldb + kk + kg * 8, &lB[u * 8]);
        }
        __syncthreads();   // compiler drains vmcnt before barrier
        bf16x8 av[4], bv[4];
        for (int m = 0; m < 4; ++m)
            av[m] = *(const bf16x8*)&lA[(g * 128 + wr * 64 + m * 16 + rr) * 8];
        for (int n = 0; n < 4; ++n)
            bv[n] = *(const bf16x8*)&lB[(g * 128 + wc * 64 + n * 16 + rr) * 8];
        for (int m = 0; m < 4; ++m)
            for (int n = 0; n < 4; ++n)
                acc[m][n] = __builtin_amdgcn_mfma_f32_16x16x32_bf16(av[m], bv[n], acc[m][n], 0, 0, 0);
        __syncthreads();
    }

    for (int n = 0; n < 4; ++n) {
        int gc = col0 + wc * 64 + n * 16 + rr;
        float bb = bias ? bias[gc] : 0.f;
        for (int m = 0; m < 4; ++m) {
            int gr = row0 + wr * 64 + m * 16 + g * 4;   // C/D: col=lane&15, row=4*(lane>>4)+q
            for (int q = 0; q < 4; ++q)
                C[(long)(gr + q) * ldc + gc] = acc[m][n][q] + bb;
        }
    }
}

// ---------------- persistent-weight cooperative recurrence, v2.1 ----------------
// W-blocks 0..31: own h-slice [i*16,i*16+16) of ALL gates + Wcc2 rows; gh stays in LDS;
//   GRU elementwise local with f32 register h-carry; publish 1KB bf16 h_new slice.
//   Deferred: ho(t-2) = tanh(Wcc2@hn(t-2) + y1(t-2) + b_cc) on waves 6-7.
// B-blocks 32..63: attention for batch b: scores/softmax from enc (LDS),
//   y1 = sum_s al[s]*encW[b][s][:] (== Wcc1@ctx), published f32 DOUBLE-BUFFERED.
struct WSm2 {
    short h_all[Bn * Hn];     // frozen h(t-1), bf16, swizzled (32 KB)
    short hnb[2][Bn * Hn];    // raw h_new dbuf, swizzled     (64 KB)
    float gh_sl[3 * 16 * 32]; // gh slice [g][row][b]          (6 KB)
    float y1l[Bn * 16];       // y1(t-2) slice [b][jj]         (2 KB)
    int   flen[Bn];
};
struct BSm2 {
    short encl[Sn * 520];     // enc[b] bf16, rows padded 520 (66.6 KB)
    short encWl[Sn * Hn];     // encW[b] bf16                  (64 KB)
    float scp[8][64];
    float al[64];
    short hnf[Hn];            // h_new(t)[b] staged
};
union USm2 { WSm2 w; BSm2 b; };

__device__ __forceinline__ void sig_flag(unsigned* slot, unsigned val) {
    asm volatile("s_waitcnt vmcnt(0)" ::: "memory");   // drain this wave's global stores
    __syncthreads();                                   // all waves drained
    if (threadIdx.x == 0)
        __hip_atomic_store(slot, val, __ATOMIC_RELAXED, __HIP_MEMORY_SCOPE_AGENT);
}
__device__ __forceinline__ void wait_flags32(const unsigned* base, unsigned need) {
    if (threadIdx.x < 32) {
        while (__hip_atomic_load(base + threadIdx.x * 32, __ATOMIC_RELAXED, __HIP_MEMORY_SCOPE_AGENT) < need)
            __builtin_amdgcn_s_sleep(1);
    }
    __syncthreads();
}

__global__ __launch_bounds__(512, 1) void k_seq(
    const float* __restrict__ GX, const float* __restrict__ enc,
    const void* __restrict__ maskp, const int* __restrict__ fra,
    const float* __restrict__ h0,
    const short* __restrict__ Whh_b, const float* __restrict__ b_hh,
    const short* __restrict__ Wcc2_b, const float* __restrict__ b_cc,
    const float* __restrict__ encW,
    short* __restrict__ ho_out,
    unsigned long long* __restrict__ hn_pub,   // [2][32][128] u64 (4xbf16)
    float* __restrict__ y1_pub,                // [2][32][512] f32 (dbuf!)
    unsigned* __restrict__ flags)              // [2][32][32]: W / B
{
    __shared__ __align__(16) USm2 sm;
    const int bid = blockIdx.x;
    const int tid = threadIdx.x;
    const int wv = tid >> 6, lane = tid & 63;
    unsigned* flagW = flags;
    unsigned* flagB = flags + 1024;

    if (bid < Bn) {
        // ================= W-block =================
        bf16x8 afr[16];
        if (wv < 6) {          // gh A-frags: gate g = wv>>1 (n=wv&1 waves share data)
            const int g = wv >> 1;
            const int row = g * 512 + bid * 16 + (lane & 15);
            #pragma unroll
            for (int k = 0; k < 16; ++k)
                afr[k] = *(const bf16x8*)(Whh_b + (long)row * 512 + k * 32 + (lane >> 4) * 8);
        } else {               // ho A-frags: Wcc2 rows bid*16..
            const int row = bid * 16 + (lane & 15);
            #pragma unroll
            for (int k = 0; k < 16; ++k)
                afr[k] = *(const bf16x8*)(Wcc2_b + (long)row * 512 + k * 32 + (lane >> 4) * 8);
        }
        if (tid < Bn) sm.w.flen[tid] = fra[tid];
        // h_all init from h0 (f32 -> bf16, swizzled)
        #pragma unroll
        for (int it = 0; it < 8; ++it) {
            const int idx2 = it * 512 + tid;          // 8B unit: b*128 + ci2
            const int b = idx2 >> 7, ci2 = idx2 & 127;
            const int j0 = ci2 * 4;
            const int soff = b * 512 + ((((ci2 >> 1)) ^ (b & 7)) << 3) + (ci2 & 1) * 4;
            const float4 v = *(const float4*)(h0 + b * 512 + j0);
            unsigned long long pk = (unsigned long long)(unsigned short)f2bf(v.x)
                                  | ((unsigned long long)(unsigned short)f2bf(v.y) << 16)
                                  | ((unsigned long long)(unsigned short)f2bf(v.z) << 32)
                                  | ((unsigned long long)(unsigned short)f2bf(v.w) << 48);
            *(unsigned long long*)&sm.w.h_all[soff] = pk;
        }

        const int eb = tid >> 4, jj = tid & 15;       // elementwise mapping (batch, slice-row)
        float h_carry = h0[eb * 512 + bid * 16 + jj]; // f32 carried state (this thread's element)
        const int flen_e = fra[eb];

        for (int t = 0; t <= Tn + 1; ++t) {
            // A: prefetch gx slice for step t
            float gxr = 0.f, gxz = 0.f, gxn = 0.f;
            if (t < Tn) {
                const long base = (long)(eb * Tn + t) * H3 + bid * 16 + jj;
                gxr = GX[base]; gxz = GX[base + 512]; gxn = GX[base + 1024];
            }
            // B: stage hn(t-1) + freeze-merge into h_all (bf16, MFMA input only)
            if (t >= 1 && t <= Tn) {
                wait_flags32(flagW, (unsigned)t);
                const unsigned long long* src = hn_pub + ((t - 1) & 1) * 4096;
                short* dst = sm.w.hnb[(t - 1) & 1];
                #pragma unroll
                for (int it = 0; it < 8; ++it) {
                    const int idx2 = it * 512 + tid;
                    const int b = idx2 >> 7, ci2 = idx2 & 127;
                    const int soff = b * 512 + ((((ci2 >> 1)) ^ (b & 7)) << 3) + (ci2 & 1) * 4;
                    const unsigned long long v = __hip_atomic_load(src + idx2, __ATOMIC_RELAXED, __HIP_MEMORY_SCOPE_AGENT);
                    *(unsigned long long*)&dst[soff] = v;
                    if (t - 1 < sm.w.flen[b]) *(unsigned long long*)&sm.w.h_all[soff] = v;
                }
            }
            // C: stage y1(t-2) from dbuf slot (t-2)&1
            if (t >= 2) {
                wait_flags32(flagB, (unsigned)(t - 1));
                sm.w.y1l[tid] = __hip_atomic_load(
                    y1_pub + ((t - 2) & 1) * (Bn * Hn) + (tid >> 4) * 512 + bid * 16 + (tid & 15),
                    __ATOMIC_RELAXED, __HIP_MEMORY_SCOPE_AGENT);
            }
            __syncthreads();
            // E1: gh(t) slice (waves 0-5)
            if (t < Tn && wv < 6) {
                const int g = wv >> 1, n = wv & 1;
                const int bq = n * 16 + (lane & 15);
                f32x4 acc = {0.f, 0.f, 0.f, 0.f};
                #pragma unroll
                for (int k = 0; k < 16; ++k) {
                    const int c = k * 4 + (lane >> 4);
                    bf16x8 bfr = *(const bf16x8*)&sm.w.h_all[bq * 512 + ((c ^ (bq & 7)) << 3)];
                    acc = __builtin_amdgcn_mfma_f32_16x16x32_bf16(afr[k], bfr, acc, 0, 0, 0);
                }
                const int r0 = (lane >> 4) * 4;
                #pragma unroll
                for (int q = 0; q < 4; ++q)
                    sm.w.gh_sl[g * 512 + (r0 + q) * 32 + bq] = acc[q];
            }
            // E2: ho(t-2) (waves 6-7)
            if (t >= 2 && wv >= 6) {
                const int n = wv - 6;
                const int bq = n * 16 + (lane & 15);
                const short* hsrc = sm.w.hnb[(t - 2) & 1];
                f32x4 acc = {0.f, 0.f, 0.f, 0.f};
                #pragma unroll
                for (int k = 0; k < 16; ++k) {
                    const int c = k * 4 + (lane >> 4);
                    bf16x8 bfr = *(const bf16x8*)&hsrc[bq * 512 + ((c ^ (bq & 7)) << 3)];
                    acc = __builtin_amdgcn_mfma_f32_16x16x32_bf16(afr[k], bfr, acc, 0, 0, 0);
                }
                const int r0 = (lane >> 4) * 4;
                short4 o;
                o.x = f2bf(tanhf(acc[0] + sm.w.y1l[bq * 16 + r0 + 0] + b_cc[bid * 16 + r0 + 0]));
                o.y = f2bf(tanhf(acc[1] + sm.w.y1l[bq * 16 + r0 + 1] + b_cc[bid * 16 + r0 + 1]));
                o.z = f2bf(tanhf(acc[2] + sm.w.y1l[bq * 16 + r0 + 2] + b_cc[bid * 16 + r0 + 2]));
                o.w = f2bf(tanhf(acc[3] + sm.w.y1l[bq * 16 + r0 + 3] + b_cc[bid * 16 + r0 + 3]));
                *(short4*)(ho_out + ((long)(bq * Tn + (t - 2))) * Hn + bid * 16 + r0) = o;
            }
            __syncthreads();
            // G: GRU elementwise (f32 carry) + publish h_new(t) slice
            if (t < Tn) {
                const int j = bid * 16 + jj;
                const float ghr = sm.w.gh_sl[jj * 32 + eb]          + b_hh[j];
                const float ghz = sm.w.gh_sl[512 + jj * 32 + eb]    + b_hh[512 + j];
                const float ghn = sm.w.gh_sl[1024 + jj * 32 + eb]   + b_hh[1024 + j];
                const float r = 1.f / (1.f + expf(-(gxr + ghr)));
                const float z = 1.f / (1.f + expf(-(gxz + ghz)));
                const float nn = tanhf(gxn + r * ghn);
                const float hv = (1.f - z) * nn + z * h_carry;   // raw h_new (f32)
                h_carry = (t < flen_e) ? hv : h_carry;           // freeze finished sequences
                int w32 = (int)(unsigned short)f2bf(hv);
                int n1 = __shfl_down(w32, 1);
                int n2 = __shfl_down(w32, 2);
                int n3 = __shfl_down(w32, 3);
                if ((jj & 3) == 0) {
                    unsigned long long pk = (unsigned long long)(unsigned)(w32 | (n1 << 16))
                                          | ((unsigned long long)(unsigned)(n2 | (n3 << 16)) << 32);
                    __hip_atomic_store(hn_pub + (t & 1) * 4096 + eb * 128 + bid * 4 + (jj >> 2), pk,
                                       __ATOMIC_RELAXED, __HIP_MEMORY_SCOPE_AGENT);
                }
                sig_flag(flagW + bid * 32, (unsigned)(t + 1));
            }
        }
    } else {
        // ================= B-block (attention, off critical path) =================
        const int b = bid - Bn;
        const unsigned w0 = ((const unsigned*)maskp)[0];
        const int mmode = (w0 == 1u) ? 0 : (w0 == 0x3F800000u ? 2 : 1);  // int32 / f32 / byte
        {   // enc[b] -> LDS bf16
            const float* encb = enc + (long)b * (Sn * Hn);
            #pragma unroll
            for (int it = 0; it < 16; ++it) {
                int e = (it * 512 + tid) * 4;
                float4 v = *(const float4*)(encb + e);
                int s = e >> 9, k = e & 511;
                short4 o; o.x = f2bf(v.x); o.y = f2bf(v.y); o.z = f2bf(v.z); o.w = f2bf(v.w);
                *(short4*)(sm.b.encl + s * 520 + k) = o;
            }
        }
        {   // encW[b] -> LDS bf16
            const float* ewb = encW + (long)b * (Sn * Hn);
            #pragma unroll
            for (int it = 0; it < 16; ++it) {
                int e = (it * 512 + tid) * 4;
                float4 v = *(const float4*)(ewb + e);
                short4 o; o.x = f2bf(v.x); o.y = f2bf(v.y); o.z = f2bf(v.z); o.w = f2bf(v.w);
                *(short4*)(sm.b.encWl + e) = o;
            }
        }

        for (int u = 0; u < Tn; ++u) {
            wait_flags32(flagW, (unsigned)(u + 1));
            if (tid < 128) {   // stage h_new(u)[b]
                unsigned long long v = __hip_atomic_load(hn_pub + (u & 1) * 4096 + b * 128 + tid,
                                                         __ATOMIC_RELAXED, __HIP_MEMORY_SCOPE_AGENT);
                *(unsigned long long*)&sm.b.hnf[tid * 4] = v;
            }
            __syncthreads();
            {   // score partials: wave `sub` covers k-slice, lane = s
                const int s = tid & 63, sub = tid >> 6;
                const short* erow = sm.b.encl + s * 520 + sub * 64;
                const short* hrow = sm.b.hnf + sub * 64;
                float p = 0.f;
                #pragma unroll
                for (int c8 = 0; c8 < 8; ++c8) {
                    bf16x8 ev = *(const bf16x8*)(erow + c8 * 8);
                    bf16x8 hv8 = *(const bf16x8*)(hrow + c8 * 8);
                    #pragma unroll
                    for (int e = 0; e < 8; ++e)
                        p += bf2f(ev[e]) * bf2f(hv8[e]);
                }
                sm.b.scp[sub][s] = p;
            }
            __syncthreads();
            if (tid < 64) {    // mask + softmax
                float v = 0.f;
                #pragma unroll
                for (int q = 0; q < 8; ++q) v += sm.b.scp[q][tid];
                bool mv;
                if (mmode == 0)      mv = ((const int*)maskp)[b * Sn + tid] != 0;
                else if (mmode == 1) mv = ((const unsigned char*)maskp)[b * Sn + tid] != 0;
                else                 mv = ((const float*)maskp)[b * Sn + tid] != 0.f;
                v = mv ? v : -__builtin_inff();
                float mx = v;
                for (int o = 1; o < 64; o <<= 1) mx = fmaxf(mx, __shfl_xor(mx, o));
                float e = expf(v - mx);
                float su = e;
                for (int o = 1; o < 64; o <<= 1) su += __shfl_xor(su, o);
                sm.b.al[tid] = e / su;
            }
            __syncthreads();
            {   // y1 = sum_s al[s] * encW[b][s][:]  (== Wcc1 @ ctx), publish to dbuf slot u&1
                float acc = 0.f;
                #pragma unroll 8
                for (int s = 0; s < 64; ++s)
                    acc += sm.b.al[s] * bf2f(sm.b.encWl[s * 512 + tid]);
                __hip_atomic_store(y1_pub + (u & 1) * (Bn * Hn) + b * 512 + tid, acc,
                                   __ATOMIC_RELAXED, __HIP_MEMORY_SCOPE_AGENT);
            }
            sig_flag(flagB + b * 32, (unsigned)(u + 1));
        }
    }
}

// ---------------- in-place log-softmax over V=32000 per row (online max+sum) ----------------
__global__ __launch_bounds__(256) void k_logsoftmax(float* __restrict__ out) {
    const long row = blockIdx.x;
    float* p = out + row * (long)Vn;
    const int tid = threadIdx.x;
    __shared__ float redm[4];
    __shared__ float reds[4];

    float mx = -__builtin_inff(), sm = 0.f;
    for (int i = tid; i < Vn / 4; i += 256) {
        float4 v = *(const float4*)(p + i * 4);
        float e0 = v.x, e1 = v.y, e2 = v.z, e3 = v.w;
        float m01 = fmaxf(e0, e1), m23 = fmaxf(e2, e3);
        float ml = fmaxf(m01, m23);
        float nm = fmaxf(mx, ml);
        sm = sm * __expf(mx - nm) + __expf(e0 - nm) + __expf(e1 - nm) + __expf(e2 - nm) + __expf(e3 - nm);
        mx = nm;
    }
    for (int o = 1; o < 64; o <<= 1) {
        float omx = __shfl_xor(mx, o), osm = __shfl_xor(sm, o);
        float nm = fmaxf(mx, omx);
        sm = sm * __expf(mx - nm) + osm * __expf(omx - nm);
        mx = nm;
    }
    if ((tid & 63) == 0) { redm[tid >> 6] = mx; reds[tid >> 6] = sm; }
    __syncthreads();
    float gmx = fmaxf(fmaxf(redm[0], redm[1]), fmaxf(redm[2], redm[3]));
    float gsm = reds[0] * __expf(redm[0] - gmx) + reds[1] * __expf(redm[1] - gmx)
              + reds[2] * __expf(redm[2] - gmx) + reds[3] * __expf(redm[3] - gmx);
    const float lse = gmx + logf(gsm);

    for (int i = tid; i < Vn / 4; i += 256) {
        float4 v = *(const float4*)(p + i * 4);
        v.x -= lse; v.y -= lse; v.z -= lse; v.w -= lse;
        *(float4*)(p + i * 4) = v;
    }
}

extern "C" void kernel_launch(void* const* d_in, const int* in_sizes, int n_in,
                              void* d_out, int out_size, void* d_ws, size_t ws_size,
                              hipStream_t stream) {
    const float* enc   = (const float*)d_in[0];
    const float* h0    = (const float*)d_in[1];
    const void*  maskp = d_in[2];
    const int*   tgt   = (const int*)d_in[3];
    const int*   fra   = (const int*)d_in[4];
    const float* emb   = (const float*)d_in[5];
    const float* W_ih  = (const float*)d_in[6];
    const float* W_hh  = (const float*)d_in[7];
    const float* b_ih  = (const float*)d_in[8];
    const float* b_hh  = (const float*)d_in[9];
    const float* W_cc  = (const float*)d_in[10];
    const float* b_cc  = (const float*)d_in[11];
    const float* W_out = (const float*)d_in[12];
    const float* b_out = (const float*)d_in[13];
    float* out = (float*)d_out;

    char* ws = (char*)d_ws;
    float*    GX      = (float*)ws;   ws += (long)2048 * 1536 * 4;  // 12.58 MB
    float*    encW_ws = (float*)ws;   ws += (long)2048 * 512 * 4;   //  4.19 MB
    short*    Xb      = (short*)ws;   ws += (long)2048 * 512 * 2;   //  2.10 MB
    short*    Wih_b   = (short*)ws;   ws += (long)1536 * 512 * 2;   //  1.57 MB
    short*    Wout_b  = (short*)ws;   ws += (long)32000 * 512 * 2;  // 32.77 MB
    short*    Whh_b   = (short*)ws;   ws += (long)1536 * 512 * 2;   //  1.57 MB
    short*    Wc1_b   = (short*)ws;   ws += (long)512 * 512 * 2;    //  0.52 MB
    short*    Wcc2_b  = (short*)ws;   ws += (long)512 * 512 * 2;    //  0.52 MB
    short*    enc_b   = (short*)ws;   ws += (long)2048 * 512 * 2;   //  2.10 MB
    short*    ho_b    = (short*)ws;   ws += (long)2048 * 512 * 2;   //  2.10 MB
    unsigned long long* hn_pub = (unsigned long long*)ws; ws += (long)2 * 4096 * 8;   // 64 KB
    float*    y1_pub  = (float*)ws;   ws += (long)2 * 32 * 512 * 4; // 128 KB (dbuf)
    unsigned* flags   = (unsigned*)ws; ws += 2 * 1024 * 4;          // 8 KB

    // --- prep / converts
    k_gather<<<2048, 128, 0, stream>>>(tgt, emb, Xb);
    k_cvt<<<768, 256, 0, stream>>>(W_ih, 512, 0, Wih_b, (long)1536 * 512 / 4);
    k_cvt<<<4096, 256, 0, stream>>>(W_out, 512, 0, Wout_b, (long)32000 * 512 / 4);
    k_cvt<<<768, 256, 0, stream>>>(W_hh, 512, 0, Whh_b, (long)1536 * 512 / 4);
    k_cvt<<<256, 256, 0, stream>>>(W_cc, 1024, 0, Wc1_b, (long)512 * 512 / 4);    // Wc1 = W_cc[:, :512]
    k_cvt<<<256, 256, 0, stream>>>(W_cc, 1024, 512, Wcc2_b, (long)512 * 512 / 4); // Wc2 = W_cc[:, 512:]
    k_cvt<<<1024, 256, 0, stream>>>(enc, 512, 0, enc_b, (long)2048 * 512 / 4);

    // --- GX = X @ W_ih^T + b_ih   (M=2048, N=1536, K=512)
    k_gemm_bf16<<<dim3(12, 16), 256, 0, stream>>>(Xb, 512, Wih_b, 512, b_ih, GX, 1536, 512);
    // --- encW = enc @ Wc1^T       (M=2048, N=512, K=512)
    k_gemm_bf16<<<dim3(4, 16), 256, 0, stream>>>(enc_b, 512, Wc1_b, 512, nullptr, encW_ws, 512, 512);

    // --- cooperative recurrence
    hipMemsetAsync(flags, 0, 2 * 1024 * 4, stream);
    k_seq<<<NBLK, 512, 0, stream>>>(GX, enc, maskp, fra, h0,
                                    Whh_b, b_hh, Wcc2_b, b_cc, encW_ws,
                                    ho_b, hn_pub, y1_pub, flags);

    // --- logits = ho @ W_out^T + b_out   (M=2048, N=32000, K=512) -> d_out
    k_gemm_bf16<<<dim3(250, 16), 256, 0, stream>>>(ho_b, 512, Wout_b, 512, b_out, out, 32000, 512);

    // --- in-place log_softmax over V
    k_logsoftmax<<<2048, 256, 0, stream>>>(out);
}

// Round 8
// 750.997 us; speedup vs baseline: 10.8918x; 1.0047x over previous
//
#include <hip/hip_runtime.h>

static constexpr int Bn = 32, Sn = 64, Tn = 64, Hn = 512, Vn = 32000;
static constexpr int H3 = 1536;   // 3*H
static constexpr int NBLK = 64;   // 32 weight/GRU-blocks + 32 attention-blocks

typedef __attribute__((ext_vector_type(8))) short bf16x8;
typedef __attribute__((ext_vector_type(4))) float f32x4;

__device__ __forceinline__ short f2bf(float f) {
    unsigned u = __float_as_uint(f);
    u += 0x7FFFu + ((u >> 16) & 1u);   // round-to-nearest-even
    return (short)(u >> 16);
}
__device__ __forceinline__ float bf2f(short s) {
    return __uint_as_float(((unsigned)(unsigned short)s) << 16);
}

// async global->LDS, 16B per lane (dest must be linear in lane order)
__device__ __forceinline__ void gload16(const void* g, void* l) {
    __builtin_amdgcn_global_load_lds(
        (const __attribute__((address_space(1))) unsigned int*)g,
        (__attribute__((address_space(3))) unsigned int*)l, 16, 0, 0);
}

// ---------------- prep: gather embedding rows -> bf16 ----------------
__global__ __launch_bounds__(128) void k_gather(const int* __restrict__ tgt,
                                                const float* __restrict__ emb,
                                                short* __restrict__ Xb) {
    int m = blockIdx.x;
    int c = threadIdx.x * 4;
    const float4 v = *(const float4*)(emb + (long)tgt[m] * Hn + c);
    short4 o; o.x = f2bf(v.x); o.y = f2bf(v.y); o.z = f2bf(v.z); o.w = f2bf(v.w);
    *(short4*)(Xb + (long)m * Hn + c) = o;
}

// ---------------- prep: f32 -> bf16 (dst rows of 512; strided src with col offset) ----------------
__global__ __launch_bounds__(256) void k_cvt(const float* __restrict__ src, int src_ld, int src_off,
                                             short* __restrict__ dst, long total4) {
    for (long i = (long)blockIdx.x * 256 + threadIdx.x; i < total4; i += (long)gridDim.x * 256) {
        long e = i * 4;
        long r = e >> 9; int c = (int)(e & 511);
        const float4 v = *(const float4*)(src + r * (long)src_ld + src_off + c);
        short4 o; o.x = f2bf(v.x); o.y = f2bf(v.y); o.z = f2bf(v.z); o.w = f2bf(v.w);
        *(short4*)(dst + e) = o;
    }
}

// ---------------- generic bf16 MFMA GEMM:  C[m][n] = sum_k A[m][k]*B[n][k] (+bias[n]) ----------------
__global__ __launch_bounds__(256) void k_gemm_bf16(const short* __restrict__ A, int lda,
                                                   const short* __restrict__ Bm, int ldb,
                                                   const float* __restrict__ bias,
                                                   float* __restrict__ C, int ldc, int K) {
    __shared__ short lA[4096];
    __shared__ short lB[4096];
    const int tid = threadIdx.x;
    const int row0 = blockIdx.y * 128;
    const int col0 = blockIdx.x * 128;
    const int lane = tid & 63;
    const int w = tid >> 6;
    const int wr = w >> 1, wc = w & 1;
    const int g = lane >> 4, rr = lane & 15;

    f32x4 acc[4][4];
    for (int m = 0; m < 4; ++m)
        for (int n = 0; n < 4; ++n)
            for (int q = 0; q < 4; ++q) acc[m][n][q] = 0.f;

    for (int kk = 0; kk < K; kk += 32) {
        for (int p = 0; p < 2; ++p) {
            int u = p * 256 + tid;
            int kg = u >> 7, r = u & 127;
            gload16(A + (long)(row0 + r) * lda + kk + kg * 8, &lA[u * 8]);
            gload16(Bm + (long)(col0 + r) * ldb + kk + kg * 8, &lB[u * 8]);
        }
        __syncthreads();   // compiler drains vmcnt before barrier
        bf16x8 av[4], bv[4];
        for (int m = 0; m < 4; ++m)
            av[m] = *(const bf16x8*)&lA[(g * 128 + wr * 64 + m * 16 + rr) * 8];
        for (int n = 0; n < 4; ++n)
            bv[n] = *(const bf16x8*)&lB[(g * 128 + wc * 64 + n * 16 + rr) * 8];
        for (int m = 0; m < 4; ++m)
            for (int n = 0; n < 4; ++n)
                acc[m][n] = __builtin_amdgcn_mfma_f32_16x16x32_bf16(av[m], bv[n], acc[m][n], 0, 0, 0);
        __syncthreads();
    }

    for (int n = 0; n < 4; ++n) {
        int gc = col0 + wc * 64 + n * 16 + rr;
        float bb = bias ? bias[gc] : 0.f;
        for (int m = 0; m < 4; ++m) {
            int gr = row0 + wr * 64 + m * 16 + g * 4;   // C/D: col=lane&15, row=4*(lane>>4)+q
            for (int q = 0; q < 4; ++q)
                C[(long)(gr + q) * ldc + gc] = acc[m][n][q] + bb;
        }
    }
}

// ---------------- persistent-weight cooperative recurrence, v2.2 ----------------
// Critical-path reorder: per W iter  B(stage hn) -> E1(gh) -> G(elementwise+publish+signal)
// then slack work C(y1 wait/stage) -> E2(ho).  y1_pub TRIPLE-buffered (see WAR analysis).
struct WSm2 {
    short h_all[Bn * Hn];     // frozen h(t-1), bf16, swizzled (32 KB)
    short hnb[2][Bn * Hn];    // raw h_new dbuf, swizzled     (64 KB)
    float gh_sl[3 * 16 * 32]; // gh slice [g][row][b]          (6 KB)
    float y1l[Bn * 16];       // y1(t-2) slice [b][jj]         (2 KB)
    int   flen[Bn];
};
struct BSm2 {
    short encl[Sn * 520];     // enc[b] bf16, rows padded 520 (66.6 KB)
    short encWl[Sn * Hn];     // encW[b] bf16                  (64 KB)
    float scp[8][64];
    float al[64];
    short hnf[Hn];            // h_new(t)[b] staged
};
union USm2 { WSm2 w; BSm2 b; };

__device__ __forceinline__ void sig_flag(unsigned* slot, unsigned val) {
    asm volatile("s_waitcnt vmcnt(0)" ::: "memory");   // drain this wave's global stores
    __syncthreads();                                   // all waves drained
    if (threadIdx.x == 0)
        __hip_atomic_store(slot, val, __ATOMIC_RELAXED, __HIP_MEMORY_SCOPE_AGENT);
}
__device__ __forceinline__ void wait_flags32(const unsigned* base, unsigned need) {
    if (threadIdx.x < 32) {
        while (__hip_atomic_load(base + threadIdx.x * 32, __ATOMIC_RELAXED, __HIP_MEMORY_SCOPE_AGENT) < need)
            __builtin_amdgcn_s_sleep(1);
    }
    __syncthreads();
}

__global__ __launch_bounds__(512, 1) void k_seq(
    const float* __restrict__ GX, const float* __restrict__ enc,
    const void* __restrict__ maskp, const int* __restrict__ fra,
    const float* __restrict__ h0,
    const short* __restrict__ Whh_b, const float* __restrict__ b_hh,
    const short* __restrict__ Wcc2_b, const float* __restrict__ b_cc,
    const float* __restrict__ encW,
    short* __restrict__ ho_out,
    unsigned long long* __restrict__ hn_pub,   // [2][32][128] u64 (4xbf16)
    float* __restrict__ y1_pub,                // [3][32][512] f32 (triple buf)
    unsigned* __restrict__ flags)              // [2][32][32]: W / B
{
    __shared__ __align__(16) USm2 sm;
    const int bid = blockIdx.x;
    const int tid = threadIdx.x;
    const int wv = tid >> 6, lane = tid & 63;
    unsigned* flagW = flags;
    unsigned* flagB = flags + 1024;

    if (bid < Bn) {
        // ================= W-block =================
        bf16x8 afr[16];
        if (wv < 6) {          // gh A-frags: gate g = wv>>1 (n=wv&1 waves share data)
            const int g = wv >> 1;
            const int row = g * 512 + bid * 16 + (lane & 15);
            #pragma unroll
            for (int k = 0; k < 16; ++k)
                afr[k] = *(const bf16x8*)(Whh_b + (long)row * 512 + k * 32 + (lane >> 4) * 8);
        } else {               // ho A-frags: Wcc2 rows bid*16..
            const int row = bid * 16 + (lane & 15);
            #pragma unroll
            for (int k = 0; k < 16; ++k)
                afr[k] = *(const bf16x8*)(Wcc2_b + (long)row * 512 + k * 32 + (lane >> 4) * 8);
        }
        if (tid < Bn) sm.w.flen[tid] = fra[tid];
        // h_all init from h0 (f32 -> bf16, swizzled)
        #pragma unroll
        for (int it = 0; it < 8; ++it) {
            const int idx2 = it * 512 + tid;          // 8B unit: b*128 + ci2
            const int b = idx2 >> 7, ci2 = idx2 & 127;
            const int j0 = ci2 * 4;
            const int soff = b * 512 + ((((ci2 >> 1)) ^ (b & 7)) << 3) + (ci2 & 1) * 4;
            const float4 v = *(const float4*)(h0 + b * 512 + j0);
            unsigned long long pk = (unsigned long long)(unsigned short)f2bf(v.x)
                                  | ((unsigned long long)(unsigned short)f2bf(v.y) << 16)
                                  | ((unsigned long long)(unsigned short)f2bf(v.z) << 32)
                                  | ((unsigned long long)(unsigned short)f2bf(v.w) << 48);
            *(unsigned long long*)&sm.w.h_all[soff] = pk;
        }

        const int eb = tid >> 4, jj = tid & 15;       // elementwise mapping (batch, slice-row)
        float h_carry = h0[eb * 512 + bid * 16 + jj]; // f32 carried state (this thread's element)
        const int flen_e = fra[eb];

        for (int t = 0; t <= Tn + 1; ++t) {
            // A: prefetch gx slice for step t
            float gxr = 0.f, gxz = 0.f, gxn = 0.f;
            if (t < Tn) {
                const long base = (long)(eb * Tn + t) * H3 + bid * 16 + jj;
                gxr = GX[base]; gxz = GX[base + 512]; gxn = GX[base + 1024];
            }
            // B: stage hn(t-1) + freeze-merge into h_all (bf16, MFMA input only)
            if (t >= 1 && t <= Tn) {
                wait_flags32(flagW, (unsigned)t);     // internal syncthreads protects hnb WAR
                const unsigned long long* src = hn_pub + ((t - 1) & 1) * 4096;
                short* dst = sm.w.hnb[(t - 1) & 1];
                #pragma unroll
                for (int it = 0; it < 8; ++it) {
                    const int idx2 = it * 512 + tid;
                    const int b = idx2 >> 7, ci2 = idx2 & 127;
                    const int soff = b * 512 + ((((ci2 >> 1)) ^ (b & 7)) << 3) + (ci2 & 1) * 4;
                    const unsigned long long v = __hip_atomic_load(src + idx2, __ATOMIC_RELAXED, __HIP_MEMORY_SCOPE_AGENT);
                    *(unsigned long long*)&dst[soff] = v;
                    if (t - 1 < sm.w.flen[b]) *(unsigned long long*)&sm.w.h_all[soff] = v;
                }
            }
            __syncthreads();
            // E1: gh(t) slice (waves 0-5), dual accumulator
            if (t < Tn && wv < 6) {
                const int g = wv >> 1, n = wv & 1;
                const int bq = n * 16 + (lane & 15);
                f32x4 a0 = {0.f, 0.f, 0.f, 0.f}, a1 = {0.f, 0.f, 0.f, 0.f};
                #pragma unroll
                for (int k = 0; k < 8; ++k) {
                    const int c0 = k * 4 + (lane >> 4);
                    const int c1 = (k + 8) * 4 + (lane >> 4);
                    bf16x8 b0 = *(const bf16x8*)&sm.w.h_all[bq * 512 + ((c0 ^ (bq & 7)) << 3)];
                    bf16x8 b1 = *(const bf16x8*)&sm.w.h_all[bq * 512 + ((c1 ^ (bq & 7)) << 3)];
                    a0 = __builtin_amdgcn_mfma_f32_16x16x32_bf16(afr[k], b0, a0, 0, 0, 0);
                    a1 = __builtin_amdgcn_mfma_f32_16x16x32_bf16(afr[k + 8], b1, a1, 0, 0, 0);
                }
                const int r0 = (lane >> 4) * 4;
                #pragma unroll
                for (int q = 0; q < 4; ++q)
                    sm.w.gh_sl[g * 512 + (r0 + q) * 32 + bq] = a0[q] + a1[q];
            }
            __syncthreads();
            // G: GRU elementwise (f32 carry) + publish h_new(t) slice + SIGNAL
            if (t < Tn) {
                const int j = bid * 16 + jj;
                const float ghr = sm.w.gh_sl[jj * 32 + eb]          + b_hh[j];
                const float ghz = sm.w.gh_sl[512 + jj * 32 + eb]    + b_hh[512 + j];
                const float ghn = sm.w.gh_sl[1024 + jj * 32 + eb]   + b_hh[1024 + j];
                const float r = 1.f / (1.f + expf(-(gxr + ghr)));
                const float z = 1.f / (1.f + expf(-(gxz + ghz)));
                const float nn = tanhf(gxn + r * ghn);
                const float hv = (1.f - z) * nn + z * h_carry;   // raw h_new (f32)
                h_carry = (t < flen_e) ? hv : h_carry;           // freeze finished sequences
                int w32 = (int)(unsigned short)f2bf(hv);
                int n1 = __shfl_down(w32, 1);
                int n2 = __shfl_down(w32, 2);
                int n3 = __shfl_down(w32, 3);
                if ((jj & 3) == 0) {
                    unsigned long long pk = (unsigned long long)(unsigned)(w32 | (n1 << 16))
                                          | ((unsigned long long)(unsigned)(n2 | (n3 << 16)) << 32);
                    __hip_atomic_store(hn_pub + (t & 1) * 4096 + eb * 128 + bid * 4 + (jj >> 2), pk,
                                       __ATOMIC_RELAXED, __HIP_MEMORY_SCOPE_AGENT);
                }
                sig_flag(flagW + bid * 32, (unsigned)(t + 1));
            }
            // C + E2 (slack work, off the hn critical path)
            if (t >= 2) {
                wait_flags32(flagB, (unsigned)(t - 1));   // internal syncthreads
                sm.w.y1l[tid] = __hip_atomic_load(
                    y1_pub + ((t - 2) % 3) * (Bn * Hn) + (tid >> 4) * 512 + bid * 16 + (tid & 15),
                    __ATOMIC_RELAXED, __HIP_MEMORY_SCOPE_AGENT);
                __syncthreads();
                if (wv >= 6) {     // ho(t-2) = tanh(Wcc2_slice @ hn(t-2) + y1(t-2) + b_cc)
                    const int n = wv - 6;
                    const int bq = n * 16 + (lane & 15);
                    const short* hsrc = sm.w.hnb[(t - 2) & 1];
                    f32x4 a0 = {0.f, 0.f, 0.f, 0.f}, a1 = {0.f, 0.f, 0.f, 0.f};
                    #pragma unroll
                    for (int k = 0; k < 8; ++k) {
                        const int c0 = k * 4 + (lane >> 4);
                        const int c1 = (k + 8) * 4 + (lane >> 4);
                        bf16x8 b0 = *(const bf16x8*)&hsrc[bq * 512 + ((c0 ^ (bq & 7)) << 3)];
                        bf16x8 b1 = *(const bf16x8*)&hsrc[bq * 512 + ((c1 ^ (bq & 7)) << 3)];
                        a0 = __builtin_amdgcn_mfma_f32_16x16x32_bf16(afr[k], b0, a0, 0, 0, 0);
                        a1 = __builtin_amdgcn_mfma_f32_16x16x32_bf16(afr[k + 8], b1, a1, 0, 0, 0);
                    }
                    const int r0 = (lane >> 4) * 4;
                    short4 o;
                    o.x = f2bf(tanhf(a0[0] + a1[0] + sm.w.y1l[bq * 16 + r0 + 0] + b_cc[bid * 16 + r0 + 0]));
                    o.y = f2bf(tanhf(a0[1] + a1[1] + sm.w.y1l[bq * 16 + r0 + 1] + b_cc[bid * 16 + r0 + 1]));
                    o.z = f2bf(tanhf(a0[2] + a1[2] + sm.w.y1l[bq * 16 + r0 + 2] + b_cc[bid * 16 + r0 + 2]));
                    o.w = f2bf(tanhf(a0[3] + a1[3] + sm.w.y1l[bq * 16 + r0 + 3] + b_cc[bid * 16 + r0 + 3]));
                    *(short4*)(ho_out + ((long)(bq * Tn + (t - 2))) * Hn + bid * 16 + r0) = o;
                }
            }
        }
    } else {
        // ================= B-block (attention, off critical path) =================
        const int b = bid - Bn;
        const unsigned w0 = ((const unsigned*)maskp)[0];
        const int mmode = (w0 == 1u) ? 0 : (w0 == 0x3F800000u ? 2 : 1);  // int32 / f32 / byte
        {   // enc[b] -> LDS bf16
            const float* encb = enc + (long)b * (Sn * Hn);
            #pragma unroll
            for (int it = 0; it < 16; ++it) {
                int e = (it * 512 + tid) * 4;
                float4 v = *(const float4*)(encb + e);
                int s = e >> 9, k = e & 511;
                short4 o; o.x = f2bf(v.x); o.y = f2bf(v.y); o.z = f2bf(v.z); o.w = f2bf(v.w);
                *(short4*)(sm.b.encl + s * 520 + k) = o;
            }
        }
        {   // encW[b] -> LDS bf16
            const float* ewb = encW + (long)b * (Sn * Hn);
            #pragma unroll
            for (int it = 0; it < 16; ++it) {
                int e = (it * 512 + tid) * 4;
                float4 v = *(const float4*)(ewb + e);
                short4 o; o.x = f2bf(v.x); o.y = f2bf(v.y); o.z = f2bf(v.z); o.w = f2bf(v.w);
                *(short4*)(sm.b.encWl + e) = o;
            }
        }

        for (int u = 0; u < Tn; ++u) {
            wait_flags32(flagW, (unsigned)(u + 1));
            if (tid < 128) {   // stage h_new(u)[b]
                unsigned long long v = __hip_atomic_load(hn_pub + (u & 1) * 4096 + b * 128 + tid,
                                                         __ATOMIC_RELAXED, __HIP_MEMORY_SCOPE_AGENT);
                *(unsigned long long*)&sm.b.hnf[tid * 4] = v;
            }
            __syncthreads();
            {   // score partials: wave `sub` covers k-slice, lane = s
                const int s = tid & 63, sub = tid >> 6;
                const short* erow = sm.b.encl + s * 520 + sub * 64;
                const short* hrow = sm.b.hnf + sub * 64;
                float p = 0.f;
                #pragma unroll
                for (int c8 = 0; c8 < 8; ++c8) {
                    bf16x8 ev = *(const bf16x8*)(erow + c8 * 8);
                    bf16x8 hv8 = *(const bf16x8*)(hrow + c8 * 8);
                    #pragma unroll
                    for (int e = 0; e < 8; ++e)
                        p += bf2f(ev[e]) * bf2f(hv8[e]);
                }
                sm.b.scp[sub][s] = p;
            }
            __syncthreads();
            if (tid < 64) {    // mask + softmax
                float v = 0.f;
                #pragma unroll
                for (int q = 0; q < 8; ++q) v += sm.b.scp[q][tid];
                bool mv;
                if (mmode == 0)      mv = ((const int*)maskp)[b * Sn + tid] != 0;
                else if (mmode == 1) mv = ((const unsigned char*)maskp)[b * Sn + tid] != 0;
                else                 mv = ((const float*)maskp)[b * Sn + tid] != 0.f;
                v = mv ? v : -__builtin_inff();
                float mx = v;
                for (int o = 1; o < 64; o <<= 1) mx = fmaxf(mx, __shfl_xor(mx, o));
                float e = expf(v - mx);
                float su = e;
                for (int o = 1; o < 64; o <<= 1) su += __shfl_xor(su, o);
                sm.b.al[tid] = e / su;
            }
            __syncthreads();
            {   // y1 = sum_s al[s] * encW[b][s][:]  (== Wcc1 @ ctx), publish to slot u%3
                float acc = 0.f;
                #pragma unroll 8
                for (int s = 0; s < 64; ++s)
                    acc += sm.b.al[s] * bf2f(sm.b.encWl[s * 512 + tid]);
                __hip_atomic_store(y1_pub + (u % 3) * (Bn * Hn) + b * 512 + tid, acc,
                                   __ATOMIC_RELAXED, __HIP_MEMORY_SCOPE_AGENT);
            }
            sig_flag(flagB + b * 32, (unsigned)(u + 1));
        }
    }
}

// ---------------- in-place log-softmax over V=32000 per row (online max+sum) ----------------
__global__ __launch_bounds__(256) void k_logsoftmax(float* __restrict__ out) {
    const long row = blockIdx.x;
    float* p = out + row * (long)Vn;
    const int tid = threadIdx.x;
    __shared__ float redm[4];
    __shared__ float reds[4];

    float mx = -__builtin_inff(), sm = 0.f;
    for (int i = tid; i < Vn / 4; i += 256) {
        float4 v = *(const float4*)(p + i * 4);
        float e0 = v.x, e1 = v.y, e2 = v.z, e3 = v.w;
        float m01 = fmaxf(e0, e1), m23 = fmaxf(e2, e3);
        float ml = fmaxf(m01, m23);
        float nm = fmaxf(mx, ml);
        sm = sm * __expf(mx - nm) + __expf(e0 - nm) + __expf(e1 - nm) + __expf(e2 - nm) + __expf(e3 - nm);
        mx = nm;
    }
    for (int o = 1; o < 64; o <<= 1) {
        float omx = __shfl_xor(mx, o), osm = __shfl_xor(sm, o);
        float nm = fmaxf(mx, omx);
        sm = sm * __expf(mx - nm) + osm * __expf(omx - nm);
        mx = nm;
    }
    if ((tid & 63) == 0) { redm[tid >> 6] = mx; reds[tid >> 6] = sm; }
    __syncthreads();
    float gmx = fmaxf(fmaxf(redm[0], redm[1]), fmaxf(redm[2], redm[3]));
    float gsm = reds[0] * __expf(redm[0] - gmx) + reds[1] * __expf(redm[1] - gmx)
              + reds[2] * __expf(redm[2] - gmx) + reds[3] * __expf(redm[3] - gmx);
    const float lse = gmx + logf(gsm);

    for (int i = tid; i < Vn / 4; i += 256) {
        float4 v = *(const float4*)(p + i * 4);
        v.x -= lse; v.y -= lse; v.z -= lse; v.w -= lse;
        *(float4*)(p + i * 4) = v;
    }
}

extern "C" void kernel_launch(void* const* d_in, const int* in_sizes, int n_in,
                              void* d_out, int out_size, void* d_ws, size_t ws_size,
                              hipStream_t stream) {
    const float* enc   = (const float*)d_in[0];
    const float* h0    = (const float*)d_in[1];
    const void*  maskp = d_in[2];
    const int*   tgt   = (const int*)d_in[3];
    const int*   fra   = (const int*)d_in[4];
    const float* emb   = (const float*)d_in[5];
    const float* W_ih  = (const float*)d_in[6];
    const float* W_hh  = (const float*)d_in[7];
    const float* b_ih  = (const float*)d_in[8];
    const float* b_hh  = (const float*)d_in[9];
    const float* W_cc  = (const float*)d_in[10];
    const float* b_cc  = (const float*)d_in[11];
    const float* W_out = (const float*)d_in[12];
    const float* b_out = (const float*)d_in[13];
    float* out = (float*)d_out;

    char* ws = (char*)d_ws;
    float*    GX      = (float*)ws;   ws += (long)2048 * 1536 * 4;  // 12.58 MB
    float*    encW_ws = (float*)ws;   ws += (long)2048 * 512 * 4;   //  4.19 MB
    short*    Xb      = (short*)ws;   ws += (long)2048 * 512 * 2;   //  2.10 MB
    short*    Wih_b   = (short*)ws;   ws += (long)1536 * 512 * 2;   //  1.57 MB
    short*    Wout_b  = (short*)ws;   ws += (long)32000 * 512 * 2;  // 32.77 MB
    short*    Whh_b   = (short*)ws;   ws += (long)1536 * 512 * 2;   //  1.57 MB
    short*    Wc1_b   = (short*)ws;   ws += (long)512 * 512 * 2;    //  0.52 MB
    short*    Wcc2_b  = (short*)ws;   ws += (long)512 * 512 * 2;    //  0.52 MB
    short*    enc_b   = (short*)ws;   ws += (long)2048 * 512 * 2;   //  2.10 MB
    short*    ho_b    = (short*)ws;   ws += (long)2048 * 512 * 2;   //  2.10 MB
    unsigned long long* hn_pub = (unsigned long long*)ws; ws += (long)2 * 4096 * 8;   // 64 KB
    float*    y1_pub  = (float*)ws;   ws += (long)3 * 32 * 512 * 4; // 192 KB (triple buf)
    unsigned* flags   = (unsigned*)ws; ws += 2 * 1024 * 4;          // 8 KB

    // --- prep / converts
    k_gather<<<2048, 128, 0, stream>>>(tgt, emb, Xb);
    k_cvt<<<768, 256, 0, stream>>>(W_ih, 512, 0, Wih_b, (long)1536 * 512 / 4);
    k_cvt<<<4096, 256, 0, stream>>>(W_out, 512, 0, Wout_b, (long)32000 * 512 / 4);
    k_cvt<<<768, 256, 0, stream>>>(W_hh, 512, 0, Whh_b, (long)1536 * 512 / 4);
    k_cvt<<<256, 256, 0, stream>>>(W_cc, 1024, 0, Wc1_b, (long)512 * 512 / 4);    // Wc1 = W_cc[:, :512]
    k_cvt<<<256, 256, 0, stream>>>(W_cc, 1024, 512, Wcc2_b, (long)512 * 512 / 4); // Wc2 = W_cc[:, 512:]
    k_cvt<<<1024, 256, 0, stream>>>(enc, 512, 0, enc_b, (long)2048 * 512 / 4);

    // --- GX = X @ W_ih^T + b_ih   (M=2048, N=1536, K=512)
    k_gemm_bf16<<<dim3(12, 16), 256, 0, stream>>>(Xb, 512, Wih_b, 512, b_ih, GX, 1536, 512);
    // --- encW = enc @ Wc1^T       (M=2048, N=512, K=512)
    k_gemm_bf16<<<dim3(4, 16), 256, 0, stream>>>(enc_b, 512, Wc1_b, 512, nullptr, encW_ws, 512, 512);

    // --- cooperative recurrence
    hipMemsetAsync(flags, 0, 2 * 1024 * 4, stream);
    k_seq<<<NBLK, 512, 0, stream>>>(GX, enc, maskp, fra, h0,
                                    Whh_b, b_hh, Wcc2_b, b_cc, encW_ws,
                                    ho_b, hn_pub, y1_pub, flags);

    // --- logits = ho @ W_out^T + b_out   (M=2048, N=32000, K=512) -> d_out
    k_gemm_bf16<<<dim3(250, 16), 256, 0, stream>>>(ho_b, 512, Wout_b, 512, b_out, out, 32000, 512);

    // --- in-place log_softmax over V
    k_logsoftmax<<<2048, 256, 0, stream>>>(out);
}

// Round 9
// 689.095 us; speedup vs baseline: 11.8702x; 1.0898x over previous
//
#include <hip/hip_runtime.h>

static constexpr int Bn = 32, Sn = 64, Tn = 64, Hn = 512, Vn = 32000;
static constexpr int H3 = 1536;   // 3*H

typedef __attribute__((ext_vector_type(8))) short bf16x8;
typedef __attribute__((ext_vector_type(4))) float f32x4;

__device__ __forceinline__ short f2bf(float f) {
    unsigned u = __float_as_uint(f);
    u += 0x7FFFu + ((u >> 16) & 1u);   // round-to-nearest-even
    return (short)(u >> 16);
}
__device__ __forceinline__ float bf2f(short s) {
    return __uint_as_float(((unsigned)(unsigned short)s) << 16);
}

// async global->LDS, 16B per lane (dest must be linear in lane order)
__device__ __forceinline__ void gload16(const void* g, void* l) {
    __builtin_amdgcn_global_load_lds(
        (const __attribute__((address_space(1))) unsigned int*)g,
        (__attribute__((address_space(3))) unsigned int*)l, 16, 0, 0);
}

// ---------------- prep: gather embedding rows -> bf16 ----------------
__global__ __launch_bounds__(128) void k_gather(const int* __restrict__ tgt,
                                                const float* __restrict__ emb,
                                                short* __restrict__ Xb) {
    int m = blockIdx.x;
    int c = threadIdx.x * 4;
    const float4 v = *(const float4*)(emb + (long)tgt[m] * Hn + c);
    short4 o; o.x = f2bf(v.x); o.y = f2bf(v.y); o.z = f2bf(v.z); o.w = f2bf(v.w);
    *(short4*)(Xb + (long)m * Hn + c) = o;
}

// ---------------- prep: f32 -> bf16 (dst rows of 512; strided src with col offset) ----------------
__global__ __launch_bounds__(256) void k_cvt(const float* __restrict__ src, int src_ld, int src_off,
                                             short* __restrict__ dst, long total4) {
    for (long i = (long)blockIdx.x * 256 + threadIdx.x; i < total4; i += (long)gridDim.x * 256) {
        long e = i * 4;
        long r = e >> 9; int c = (int)(e & 511);
        const float4 v = *(const float4*)(src + r * (long)src_ld + src_off + c);
        short4 o; o.x = f2bf(v.x); o.y = f2bf(v.y); o.z = f2bf(v.z); o.w = f2bf(v.w);
        *(short4*)(dst + e) = o;
    }
}

// ---------------- generic bf16 MFMA GEMM:  C[m][n] = sum_k A[m][k]*B[n][k] (+bias[n]) ----------------
__global__ __launch_bounds__(256) void k_gemm_bf16(const short* __restrict__ A, int lda,
                                                   const short* __restrict__ Bm, int ldb,
                                                   const float* __restrict__ bias,
                                                   float* __restrict__ C, int ldc, int K) {
    __shared__ short lA[4096];
    __shared__ short lB[4096];
    const int tid = threadIdx.x;
    const int row0 = blockIdx.y * 128;
    const int col0 = blockIdx.x * 128;
    const int lane = tid & 63;
    const int w = tid >> 6;
    const int wr = w >> 1, wc = w & 1;
    const int g = lane >> 4, rr = lane & 15;

    f32x4 acc[4][4];
    for (int m = 0; m < 4; ++m)
        for (int n = 0; n < 4; ++n)
            for (int q = 0; q < 4; ++q) acc[m][n][q] = 0.f;

    for (int kk = 0; kk < K; kk += 32) {
        for (int p = 0; p < 2; ++p) {
            int u = p * 256 + tid;
            int kg = u >> 7, r = u & 127;
            gload16(A + (long)(row0 + r) * lda + kk + kg * 8, &lA[u * 8]);
            gload16(Bm + (long)(col0 + r) * ldb + kk + kg * 8, &lB[u * 8]);
        }
        __syncthreads();
        bf16x8 av[4], bv[4];
        for (int m = 0; m < 4; ++m)
            av[m] = *(const bf16x8*)&lA[(g * 128 + wr * 64 + m * 16 + rr) * 8];
        for (int n = 0; n < 4; ++n)
            bv[n] = *(const bf16x8*)&lB[(g * 128 + wc * 64 + n * 16 + rr) * 8];
        for (int m = 0; m < 4; ++m)
            for (int n = 0; n < 4; ++n)
                acc[m][n] = __builtin_amdgcn_mfma_f32_16x16x32_bf16(av[m], bv[n], acc[m][n], 0, 0, 0);
        __syncthreads();
    }

    for (int n = 0; n < 4; ++n) {
        int gc = col0 + wc * 64 + n * 16 + rr;
        float bb = bias ? bias[gc] : 0.f;
        for (int m = 0; m < 4; ++m) {
            int gr = row0 + wr * 64 + m * 16 + g * 4;   // C/D: col=lane&15, row=4*(lane>>4)+q
            for (int q = 0; q < 4; ++q)
                C[(long)(gr + q) * ldc + gc] = acc[m][n][q] + bb;
        }
    }
}

// ---------------- fused two-operand GEMM + tanh, bf16 out:  C = tanh(A1@B1^T + A2@B2^T + bias) ----------------
__global__ __launch_bounds__(256) void k_ho(const short* __restrict__ A1, const short* __restrict__ A2,
                                            const short* __restrict__ B1, const short* __restrict__ B2,
                                            const float* __restrict__ bias, short* __restrict__ C) {
    __shared__ short lA[4096];
    __shared__ short lB[4096];
    const int tid = threadIdx.x;
    const int row0 = blockIdx.y * 128;
    const int col0 = blockIdx.x * 128;
    const int lane = tid & 63;
    const int w = tid >> 6;
    const int wr = w >> 1, wc = w & 1;
    const int g = lane >> 4, rr = lane & 15;

    f32x4 acc[4][4];
    for (int m = 0; m < 4; ++m)
        for (int n = 0; n < 4; ++n)
            for (int q = 0; q < 4; ++q) acc[m][n][q] = 0.f;

    for (int ph = 0; ph < 2; ++ph) {
        const short* A = ph ? A2 : A1;
        const short* Bm = ph ? B2 : B1;
        for (int kk = 0; kk < 512; kk += 32) {
            for (int p = 0; p < 2; ++p) {
                int u = p * 256 + tid;
                int kg = u >> 7, r = u & 127;
                gload16(A + (long)(row0 + r) * 512 + kk + kg * 8, &lA[u * 8]);
                gload16(Bm + (long)(col0 + r) * 512 + kk + kg * 8, &lB[u * 8]);
            }
            __syncthreads();
            bf16x8 av[4], bv[4];
            for (int m = 0; m < 4; ++m)
                av[m] = *(const bf16x8*)&lA[(g * 128 + wr * 64 + m * 16 + rr) * 8];
            for (int n = 0; n < 4; ++n)
                bv[n] = *(const bf16x8*)&lB[(g * 128 + wc * 64 + n * 16 + rr) * 8];
            for (int m = 0; m < 4; ++m)
                for (int n = 0; n < 4; ++n)
                    acc[m][n] = __builtin_amdgcn_mfma_f32_16x16x32_bf16(av[m], bv[n], acc[m][n], 0, 0, 0);
            __syncthreads();
        }
    }

    for (int n = 0; n < 4; ++n) {
        int gc = col0 + wc * 64 + n * 16 + rr;
        float bb = bias[gc];
        for (int m = 0; m < 4; ++m) {
            int gr = row0 + wr * 64 + m * 16 + g * 4;
            for (int q = 0; q < 4; ++q)
                C[(long)(gr + q) * 512 + gc] = f2bf(tanhf(acc[m][n][q] + bb));
        }
    }
}

// ---------------- pure-GRU cooperative recurrence (32 blocks, h-slice partitioned) ----------------
__device__ __forceinline__ void sig_flag(unsigned* slot, unsigned val) {
    asm volatile("s_waitcnt vmcnt(0)" ::: "memory");   // drain this wave's global stores
    __syncthreads();                                   // all waves drained
    if (threadIdx.x == 0)
        __hip_atomic_store(slot, val, __ATOMIC_RELAXED, __HIP_MEMORY_SCOPE_AGENT);
}
__device__ __forceinline__ void wait_flags32(const unsigned* base, unsigned need) {
    if (threadIdx.x < 32) {
        while (__hip_atomic_load(base + threadIdx.x * 32, __ATOMIC_RELAXED, __HIP_MEMORY_SCOPE_AGENT) < need)
            __builtin_amdgcn_s_sleep(1);
    }
    __syncthreads();
}

__global__ __launch_bounds__(512, 1) void k_seq(
    const float* __restrict__ GX, const int* __restrict__ fra,
    const float* __restrict__ h0,
    const short* __restrict__ Whh_b, const float* __restrict__ b_hh,
    short* __restrict__ hn_all,                // [B*T][512] bf16 raw h_new
    unsigned long long* __restrict__ hn_pub,   // [2][32][128] u64 (4xbf16)
    unsigned* __restrict__ flags)              // [32][32]
{
    __shared__ __align__(16) short h_all[Bn * Hn];   // frozen h, bf16, swizzled (32 KB)
    __shared__ float gh_sl[3 * 16 * 32];             // gh slice [g][row][b] (6 KB)
    __shared__ int flen[Bn];
    const int bid = blockIdx.x;
    const int tid = threadIdx.x;
    const int wv = tid >> 6, lane = tid & 63;

    bf16x8 afr[16];
    if (wv < 6) {          // gate g = wv>>1 (the two n-halves share A data)
        const int g = wv >> 1;
        const int row = g * 512 + bid * 16 + (lane & 15);
        #pragma unroll
        for (int k = 0; k < 16; ++k)
            afr[k] = *(const bf16x8*)(Whh_b + (long)row * 512 + k * 32 + (lane >> 4) * 8);
    }
    if (tid < Bn) flen[tid] = fra[tid];
    // h_all init from h0 (f32 -> bf16, swizzled)
    #pragma unroll
    for (int it = 0; it < 8; ++it) {
        const int idx2 = it * 512 + tid;          // 8B unit: b*128 + ci2
        const int b = idx2 >> 7, ci2 = idx2 & 127;
        const int j0 = ci2 * 4;
        const int soff = b * 512 + ((((ci2 >> 1)) ^ (b & 7)) << 3) + (ci2 & 1) * 4;
        const float4 v = *(const float4*)(h0 + b * 512 + j0);
        unsigned long long pk = (unsigned long long)(unsigned short)f2bf(v.x)
                              | ((unsigned long long)(unsigned short)f2bf(v.y) << 16)
                              | ((unsigned long long)(unsigned short)f2bf(v.z) << 32)
                              | ((unsigned long long)(unsigned short)f2bf(v.w) << 48);
        *(unsigned long long*)&h_all[soff] = pk;
    }

    const int eb = tid >> 4, jj = tid & 15;       // elementwise mapping (batch, slice-col)
    float h_carry = h0[eb * 512 + bid * 16 + jj];
    const int flen_e = fra[eb];

    for (int t = 0; t < Tn; ++t) {
        // A: prefetch gx slice for step t
        const long base = (long)(eb * Tn + t) * H3 + bid * 16 + jj;
        const float gxr = GX[base];
        const float gxz = GX[base + 512];
        const float gxn = GX[base + 1024];
        // B: stage hn(t-1) with freeze-merge
        if (t >= 1) {
            wait_flags32(flags, (unsigned)t);
            const unsigned long long* src = hn_pub + ((t - 1) & 1) * 4096;
            #pragma unroll
            for (int it = 0; it < 8; ++it) {
                const int idx2 = it * 512 + tid;
                const int b = idx2 >> 7, ci2 = idx2 & 127;
                if (t - 1 < flen[b]) {
                    const int soff = b * 512 + ((((ci2 >> 1)) ^ (b & 7)) << 3) + (ci2 & 1) * 4;
                    *(unsigned long long*)&h_all[soff] =
                        __hip_atomic_load(src + idx2, __ATOMIC_RELAXED, __HIP_MEMORY_SCOPE_AGENT);
                }
            }
        }
        __syncthreads();
        // E1: gh(t) slice (waves 0-5), dual accumulator
        if (wv < 6) {
            const int g = wv >> 1, n = wv & 1;
            const int bq = n * 16 + (lane & 15);
            f32x4 a0 = {0.f, 0.f, 0.f, 0.f}, a1 = {0.f, 0.f, 0.f, 0.f};
            #pragma unroll
            for (int k = 0; k < 8; ++k) {
                const int c0 = k * 4 + (lane >> 4);
                const int c1 = (k + 8) * 4 + (lane >> 4);
                bf16x8 b0 = *(const bf16x8*)&h_all[bq * 512 + ((c0 ^ (bq & 7)) << 3)];
                bf16x8 b1 = *(const bf16x8*)&h_all[bq * 512 + ((c1 ^ (bq & 7)) << 3)];
                a0 = __builtin_amdgcn_mfma_f32_16x16x32_bf16(afr[k], b0, a0, 0, 0, 0);
                a1 = __builtin_amdgcn_mfma_f32_16x16x32_bf16(afr[k + 8], b1, a1, 0, 0, 0);
            }
            const int r0 = (lane >> 4) * 4;
            #pragma unroll
            for (int q = 0; q < 4; ++q)
                gh_sl[g * 512 + (r0 + q) * 32 + bq] = a0[q] + a1[q];
        }
        __syncthreads();
        // G: GRU elementwise (f32 carry) + publish + signal; hn_all store in slack
        {
            const int j = bid * 16 + jj;
            const float ghr = gh_sl[jj * 32 + eb]          + b_hh[j];
            const float ghz = gh_sl[512 + jj * 32 + eb]    + b_hh[512 + j];
            const float ghn = gh_sl[1024 + jj * 32 + eb]   + b_hh[1024 + j];
            const float r = 1.f / (1.f + expf(-(gxr + ghr)));
            const float z = 1.f / (1.f + expf(-(gxz + ghz)));
            const float nn = tanhf(gxn + r * ghn);
            const float hv = (1.f - z) * nn + z * h_carry;   // raw h_new (f32)
            h_carry = (t < flen_e) ? hv : h_carry;
            const short hb = f2bf(hv);
            int w32 = (int)(unsigned short)hb;
            int n1 = __shfl_down(w32, 1);
            int n2 = __shfl_down(w32, 2);
            int n3 = __shfl_down(w32, 3);
            if ((jj & 3) == 0) {
                unsigned long long pk = (unsigned long long)(unsigned)(w32 | (n1 << 16))
                                      | ((unsigned long long)(unsigned)(n2 | (n3 << 16)) << 32);
                __hip_atomic_store(hn_pub + (t & 1) * 4096 + eb * 128 + bid * 4 + (jj >> 2), pk,
                                   __ATOMIC_RELAXED, __HIP_MEMORY_SCOPE_AGENT);
            }
            sig_flag(flags + bid * 32, (unsigned)(t + 1));
            hn_all[(long)(eb * Tn + t) * Hn + bid * 16 + jj] = hb;   // slack (plain store)
        }
    }
}

// ---------------- batched attention: one block per batch b, all 64 steps at once ----------------
// scores = hn @ enc^T (MFMA), mask+softmax, ctx = al @ enc (MFMA via in-LDS transpose)
__global__ __launch_bounds__(512, 1) void k_attn(
    const float* __restrict__ enc, const short* __restrict__ hn_all,
    const void* __restrict__ maskp, short* __restrict__ ctx_b)
{
    __shared__ __align__(16) short encl[64 * 536];   // enc[b] bf16, rows padded (68.6 KB)
    __shared__ __align__(16) short hnlbuf[64 * 536]; // hn rows / later enct[512][64] swizzled
    __shared__ __align__(16) float scl[64 * 64];     // scores f32 (16 KB)
    __shared__ __align__(16) short albc[64 * 72];    // al bf16 (9.2 KB)
    const int b = blockIdx.x;
    const int tid = threadIdx.x;
    const int wv = tid >> 6, lane = tid & 63;
    const int g = lane >> 4, rr = lane & 15;

    const unsigned w0 = ((const unsigned*)maskp)[0];
    const int mmode = (w0 == 1u) ? 0 : (w0 == 0x3F800000u ? 2 : 1);  // int32 / f32 / byte

    // load enc[b] f32 -> bf16 rows [s][536]
    {
        const float* encb = enc + (long)b * (Sn * Hn);
        #pragma unroll
        for (int it = 0; it < 16; ++it) {
            int e = (it * 512 + tid) * 4;
            float4 v = *(const float4*)(encb + e);
            int s = e >> 9, k = e & 511;
            short4 o; o.x = f2bf(v.x); o.y = f2bf(v.y); o.z = f2bf(v.z); o.w = f2bf(v.w);
            *(short4*)(encl + s * 536 + k) = o;
        }
    }
    // load hn[b] rows [t][536]
    {
        const short* hb = hn_all + (long)b * (Tn * Hn);
        #pragma unroll
        for (int it = 0; it < 8; ++it) {
            int u = it * 512 + tid;
            int t = u >> 6, k8 = (u & 63) * 8;
            *(int4*)(hnlbuf + t * 536 + k8) = *(const int4*)(hb + t * 512 + k8);
        }
    }
    __syncthreads();

    // scores MFMA: M=64(t) x N=64(s) x K=512; 16 tile-tasks over 8 waves
    for (int i = 0; i < 2; ++i) {
        const int id = wv * 2 + i;
        const int tt = id >> 2, ss = id & 3;
        f32x4 a0 = {0.f, 0.f, 0.f, 0.f}, a1 = {0.f, 0.f, 0.f, 0.f};
        #pragma unroll
        for (int k = 0; k < 8; ++k) {
            bf16x8 av0 = *(const bf16x8*)&hnlbuf[(tt * 16 + rr) * 536 + k * 32 + g * 8];
            bf16x8 bv0 = *(const bf16x8*)&encl[(ss * 16 + rr) * 536 + k * 32 + g * 8];
            bf16x8 av1 = *(const bf16x8*)&hnlbuf[(tt * 16 + rr) * 536 + (k + 8) * 32 + g * 8];
            bf16x8 bv1 = *(const bf16x8*)&encl[(ss * 16 + rr) * 536 + (k + 8) * 32 + g * 8];
            a0 = __builtin_amdgcn_mfma_f32_16x16x32_bf16(av0, bv0, a0, 0, 0, 0);
            a1 = __builtin_amdgcn_mfma_f32_16x16x32_bf16(av1, bv1, a1, 0, 0, 0);
        }
        #pragma unroll
        for (int q = 0; q < 4; ++q)
            scl[(tt * 16 + g * 4 + q) * 64 + ss * 16 + rr] = a0[q] + a1[q];
    }
    __syncthreads();

    // softmax per t-row (wave wv: rows wv*8+(lane>>3); 8 lanes per row) -> al bf16 in albc
    {
        const int t = wv * 8 + (lane >> 3);
        const int sub = lane & 7;
        float v[8];
        #pragma unroll
        for (int e = 0; e < 8; ++e) {
            const int s = sub * 8 + e;
            bool mv;
            if (mmode == 0)      mv = ((const int*)maskp)[b * Sn + s] != 0;
            else if (mmode == 1) mv = ((const unsigned char*)maskp)[b * Sn + s] != 0;
            else                 mv = ((const float*)maskp)[b * Sn + s] != 0.f;
            v[e] = mv ? scl[t * 64 + s] : -__builtin_inff();
        }
        float mx = v[0];
        #pragma unroll
        for (int e = 1; e < 8; ++e) mx = fmaxf(mx, v[e]);
        mx = fmaxf(mx, __shfl_xor(mx, 1));
        mx = fmaxf(mx, __shfl_xor(mx, 2));
        mx = fmaxf(mx, __shfl_xor(mx, 4));
        float su = 0.f;
        float ev[8];
        #pragma unroll
        for (int e = 0; e < 8; ++e) { ev[e] = __expf(v[e] - mx); su += ev[e]; }
        su += __shfl_xor(su, 1);
        su += __shfl_xor(su, 2);
        su += __shfl_xor(su, 4);
        const float inv = 1.f / su;
        bf16x8 o;
        #pragma unroll
        for (int e = 0; e < 8; ++e) o[e] = f2bf(ev[e] * inv);
        *(bf16x8*)&albc[t * 72 + sub * 8] = o;
    }
    // transpose encl -> enct[512][64] (chunk-XOR swizzled) in hnlbuf
    {
        short* enct = hnlbuf;
        const int j = tid;
        #pragma unroll
        for (int c = 0; c < 8; ++c) {
            bf16x8 tmp;
            #pragma unroll
            for (int e = 0; e < 8; ++e) tmp[e] = encl[(c * 8 + e) * 536 + j];
            *(bf16x8*)&enct[j * 64 + ((c ^ (j & 7)) * 8)] = tmp;
        }
    }
    __syncthreads();

    // ctx MFMA: M=64(t) x N=512(j) x K=64(s); 128 tile-tasks over 8 waves
    {
        const short* enct = hnlbuf;
        for (int i = 0; i < 16; ++i) {
            const int id = wv * 16 + i;
            const int tt = id >> 5, jt = id & 31;
            const int jr = jt * 16 + rr;
            f32x4 acc = {0.f, 0.f, 0.f, 0.f};
            #pragma unroll
            for (int kk = 0; kk < 2; ++kk) {
                bf16x8 av = *(const bf16x8*)&albc[(tt * 16 + rr) * 72 + kk * 32 + g * 8];
                const int c = kk * 4 + g;
                bf16x8 bv = *(const bf16x8*)&enct[jr * 64 + ((c ^ (jr & 7)) * 8)];
                acc = __builtin_amdgcn_mfma_f32_16x16x32_bf16(av, bv, acc, 0, 0, 0);
            }
            #pragma unroll
            for (int q = 0; q < 4; ++q) {
                const int t = tt * 16 + g * 4 + q;
                ctx_b[(long)(b * Tn + t) * Hn + jr] = f2bf(acc[q]);
            }
        }
    }
}

// ---------------- in-place log-softmax over V=32000 per row (online max+sum) ----------------
__global__ __launch_bounds__(256) void k_logsoftmax(float* __restrict__ out) {
    const long row = blockIdx.x;
    float* p = out + row * (long)Vn;
    const int tid = threadIdx.x;
    __shared__ float redm[4];
    __shared__ float reds[4];

    float mx = -__builtin_inff(), sm = 0.f;
    for (int i = tid; i < Vn / 4; i += 256) {
        float4 v = *(const float4*)(p + i * 4);
        float ml = fmaxf(fmaxf(v.x, v.y), fmaxf(v.z, v.w));
        float nm = fmaxf(mx, ml);
        sm = sm * __expf(mx - nm) + __expf(v.x - nm) + __expf(v.y - nm) + __expf(v.z - nm) + __expf(v.w - nm);
        mx = nm;
    }
    for (int o = 1; o < 64; o <<= 1) {
        float omx = __shfl_xor(mx, o), osm = __shfl_xor(sm, o);
        float nm = fmaxf(mx, omx);
        sm = sm * __expf(mx - nm) + osm * __expf(omx - nm);
        mx = nm;
    }
    if ((tid & 63) == 0) { redm[tid >> 6] = mx; reds[tid >> 6] = sm; }
    __syncthreads();
    float gmx = fmaxf(fmaxf(redm[0], redm[1]), fmaxf(redm[2], redm[3]));
    float gsm = reds[0] * __expf(redm[0] - gmx) + reds[1] * __expf(redm[1] - gmx)
              + reds[2] * __expf(redm[2] - gmx) + reds[3] * __expf(redm[3] - gmx);
    const float lse = gmx + logf(gsm);

    for (int i = tid; i < Vn / 4; i += 256) {
        float4 v = *(const float4*)(p + i * 4);
        v.x -= lse; v.y -= lse; v.z -= lse; v.w -= lse;
        *(float4*)(p + i * 4) = v;
    }
}

extern "C" void kernel_launch(void* const* d_in, const int* in_sizes, int n_in,
                              void* d_out, int out_size, void* d_ws, size_t ws_size,
                              hipStream_t stream) {
    const float* enc   = (const float*)d_in[0];
    const float* h0    = (const float*)d_in[1];
    const void*  maskp = d_in[2];
    const int*   tgt   = (const int*)d_in[3];
    const int*   fra   = (const int*)d_in[4];
    const float* emb   = (const float*)d_in[5];
    const float* W_ih  = (const float*)d_in[6];
    const float* W_hh  = (const float*)d_in[7];
    const float* b_ih  = (const float*)d_in[8];
    const float* b_hh  = (const float*)d_in[9];
    const float* W_cc  = (const float*)d_in[10];
    const float* b_cc  = (const float*)d_in[11];
    const float* W_out = (const float*)d_in[12];
    const float* b_out = (const float*)d_in[13];
    float* out = (float*)d_out;

    char* ws = (char*)d_ws;
    float*    GX      = (float*)ws;   ws += (long)2048 * 1536 * 4;  // 12.58 MB
    short*    Xb      = (short*)ws;   ws += (long)2048 * 512 * 2;   //  2.10 MB
    short*    Wih_b   = (short*)ws;   ws += (long)1536 * 512 * 2;   //  1.57 MB
    short*    Wout_b  = (short*)ws;   ws += (long)32000 * 512 * 2;  // 32.77 MB
    short*    Whh_b   = (short*)ws;   ws += (long)1536 * 512 * 2;   //  1.57 MB
    short*    Wc1_b   = (short*)ws;   ws += (long)512 * 512 * 2;    //  0.52 MB
    short*    Wcc2_b  = (short*)ws;   ws += (long)512 * 512 * 2;    //  0.52 MB
    short*    ho_b    = (short*)ws;   ws += (long)2048 * 512 * 2;   //  2.10 MB
    short*    hn_all  = (short*)ws;   ws += (long)2048 * 512 * 2;   //  2.10 MB
    short*    ctx_b   = (short*)ws;   ws += (long)2048 * 512 * 2;   //  2.10 MB
    unsigned long long* hn_pub = (unsigned long long*)ws; ws += (long)2 * 4096 * 8;   // 64 KB
    unsigned* flags   = (unsigned*)ws; ws += 1024 * 4;              // 4 KB

    // --- prep / converts
    k_gather<<<2048, 128, 0, stream>>>(tgt, emb, Xb);
    k_cvt<<<768, 256, 0, stream>>>(W_ih, 512, 0, Wih_b, (long)1536 * 512 / 4);
    k_cvt<<<4096, 256, 0, stream>>>(W_out, 512, 0, Wout_b, (long)32000 * 512 / 4);
    k_cvt<<<768, 256, 0, stream>>>(W_hh, 512, 0, Whh_b, (long)1536 * 512 / 4);
    k_cvt<<<256, 256, 0, stream>>>(W_cc, 1024, 0, Wc1_b, (long)512 * 512 / 4);    // Wc1 = W_cc[:, :512]
    k_cvt<<<256, 256, 0, stream>>>(W_cc, 1024, 512, Wcc2_b, (long)512 * 512 / 4); // Wc2 = W_cc[:, 512:]

    // --- GX = X @ W_ih^T + b_ih   (M=2048, N=1536, K=512)
    k_gemm_bf16<<<dim3(12, 16), 256, 0, stream>>>(Xb, 512, Wih_b, 512, b_ih, GX, 1536, 512);

    // --- pure-GRU cooperative recurrence (32 blocks)
    hipMemsetAsync(flags, 0, 1024 * 4, stream);
    k_seq<<<32, 512, 0, stream>>>(GX, fra, h0, Whh_b, b_hh, hn_all, hn_pub, flags);

    // --- batched attention (one block per batch)
    k_attn<<<32, 512, 0, stream>>>(enc, hn_all, maskp, ctx_b);

    // --- ho = tanh(ctx@Wc1^T + hn@Wc2^T + b_cc) -> bf16
    k_ho<<<dim3(4, 16), 256, 0, stream>>>(ctx_b, hn_all, Wc1_b, Wcc2_b, b_cc, ho_b);

    // --- logits = ho @ W_out^T + b_out   (M=2048, N=32000, K=512) -> d_out
    k_gemm_bf16<<<dim3(250, 16), 256, 0, stream>>>(ho_b, 512, Wout_b, 512, b_out, out, 32000, 512);

    // --- in-place log_softmax over V
    k_logsoftmax<<<2048, 256, 0, stream>>>(out);
}